// Round 1
// baseline (577.405 us; speedup 1.0000x reference)
//
#include <hip/hip_runtime.h>

#define N_NODES 50000
#define N_EDGES 800000

// ---------------- helpers ----------------
__device__ __forceinline__ float wsum(float v) {
#pragma unroll
    for (int off = 32; off; off >>= 1) v += __shfl_xor(v, off);
    return v;
}

// ---------------- CSR build ----------------
__global__ void k_zero(int* __restrict__ p, int n) {
    int i = blockIdx.x * blockDim.x + threadIdx.x;
    if (i < n) p[i] = 0;
}

__global__ void k_hist(const int* __restrict__ dst, int* __restrict__ cnt, int E) {
    int e = blockIdx.x * blockDim.x + threadIdx.x;
    if (e < E) atomicAdd(&cnt[dst[e]], 1);
}

__global__ void k_scan_local(const int* __restrict__ cnt, int* __restrict__ ptr,
                             int* __restrict__ bs, int n) {
    __shared__ int tmp[256];
    int t = threadIdx.x;
    int i = blockIdx.x * 256 + t;
    int v = (i < n) ? cnt[i] : 0;
    tmp[t] = v;
    __syncthreads();
    for (int d = 1; d < 256; d <<= 1) {
        int add = (t >= d) ? tmp[t - d] : 0;
        __syncthreads();
        tmp[t] += add;
        __syncthreads();
    }
    if (i < n) ptr[i] = tmp[t] - v;  // exclusive (local)
    if (t == 255) bs[blockIdx.x] = tmp[255];
}

__global__ void k_scan_top(int* __restrict__ bs, int nb) {
    __shared__ int tmp[256];
    int t = threadIdx.x;
    int v = (t < nb) ? bs[t] : 0;
    tmp[t] = v;
    __syncthreads();
    for (int d = 1; d < 256; d <<= 1) {
        int add = (t >= d) ? tmp[t - d] : 0;
        __syncthreads();
        tmp[t] += add;
        __syncthreads();
    }
    if (t < nb) bs[t] = tmp[t] - v;  // exclusive
}

__global__ void k_scan_add(int* __restrict__ ptr, const int* __restrict__ bs,
                           int* __restrict__ cnt, int n, int E) {
    int i = blockIdx.x * 256 + threadIdx.x;
    if (i < n) {
        ptr[i] += bs[blockIdx.x];
        cnt[i] = 0;  // re-zero for scatter phase
    }
    if (i == 0) ptr[n] = E;
}

__global__ void k_scatter(const int* __restrict__ src, const int* __restrict__ dst,
                          const int* __restrict__ ptr, int* __restrict__ cnt,
                          int* __restrict__ csrc, int E) {
    int e = blockIdx.x * blockDim.x + threadIdx.x;
    if (e < E) {
        int i = dst[e];
        int pos = ptr[i] + atomicAdd(&cnt[i], 1);
        csrc[pos] = src[e];
    }
}

// ---------------- dual GEMM: Y1 = X@W1, Y2 = X@W2  (K=128 fixed) ----------------
// block = 256 threads = 32(tx) x 8(ty); 8 rows/block; CPT cols per thread over 2C cols.
template <int C, int CPT>
__global__ void k_gemm2(const float* __restrict__ X, const float* __restrict__ W1,
                        const float* __restrict__ W2, float* __restrict__ Y1,
                        float* __restrict__ Y2) {
    constexpr int K = 128, KC = 32, TC = 2 * C;
    __shared__ float xs[8][K];
    __shared__ float ws[KC][TC];
    const int t = threadIdx.x;
    const int tx = t & 31, ty = t >> 5;
    const int row = blockIdx.x * 8 + ty;
    {
        int idx = t * 4;
        int r = idx >> 7, c = idx & 127;
        *(float4*)&xs[r][c] = *(const float4*)&X[(size_t)(blockIdx.x * 8 + r) * K + c];
    }
    float acc[CPT] = {};
    const int c0 = tx * CPT;
    for (int kc = 0; kc < K; kc += KC) {
        __syncthreads();
        constexpr int NF4 = KC * TC / 4;
        constexpr int F4PT = NF4 / 256;
#pragma unroll
        for (int i = 0; i < F4PT; ++i) {
            int f = i * 256 + t;
            int k = f / (TC / 4);
            int c4 = (f % (TC / 4)) * 4;
            float4 w;
            if (c4 < C) w = *(const float4*)&W1[(size_t)(kc + k) * C + c4];
            else        w = *(const float4*)&W2[(size_t)(kc + k) * C + (c4 - C)];
            *(float4*)&ws[k][c4] = w;
        }
        __syncthreads();
#pragma unroll 8
        for (int k = 0; k < KC; ++k) {
            float xv = xs[ty][kc + k];
#pragma unroll
            for (int c4 = 0; c4 < CPT; c4 += 4) {
                float4 w = *(float4*)&ws[k][c0 + c4];
                acc[c4 + 0] = fmaf(xv, w.x, acc[c4 + 0]);
                acc[c4 + 1] = fmaf(xv, w.y, acc[c4 + 1]);
                acc[c4 + 2] = fmaf(xv, w.z, acc[c4 + 2]);
                acc[c4 + 3] = fmaf(xv, w.w, acc[c4 + 3]);
            }
        }
    }
    float* Y = (c0 < C) ? Y1 : Y2;
    const int cc = (c0 < C) ? c0 : c0 - C;
#pragma unroll
    for (int c4 = 0; c4 < CPT; c4 += 4) {
        float4 o = make_float4(acc[c4], acc[c4 + 1], acc[c4 + 2], acc[c4 + 3]);
        *(float4*)&Y[(size_t)row * C + cc + c4] = o;
    }
}

// ---------------- fused GATv2 aggregation (one wave per node*head) ----------------
// lane = channel (C=64). Online softmax over incoming edges + implicit self loop.
template <int H>
__global__ void k_gat_agg(const float* __restrict__ xl, const float* __restrict__ xr,
                          const float* __restrict__ att, const float* __restrict__ bias,
                          const int* __restrict__ ptr, const int* __restrict__ csrc,
                          float* __restrict__ out) {
    constexpr int C = 64, HC = H * C;
    const int wid = blockIdx.x * (blockDim.x >> 6) + (threadIdx.x >> 6);
    const int lane = threadIdx.x & 63;
    const int node = (H == 2) ? (wid >> 1) : wid;
    const int head = (H == 2) ? (wid & 1) : 0;
    if (node >= N_NODES) return;

    const float xri = xr[(size_t)node * HC + head * C + lane];
    const float av  = att[head * C + lane];

    // self loop first
    float xli = xl[(size_t)node * HC + head * C + lane];
    float tt = xli + xri;
    tt = tt > 0.0f ? tt : 0.2f * tt;
    float m = wsum(tt * av);
    float s = 1.0f;
    float acc = xli;

    const int e0 = ptr[node], e1 = ptr[node + 1];
    for (int e = e0; e < e1; ++e) {
        int j = csrc[e];
        float xlj = xl[(size_t)j * HC + head * C + lane];
        float u = xlj + xri;
        u = u > 0.0f ? u : 0.2f * u;
        float p = wsum(u * av);
        if (p > m) {
            float sc = __expf(m - p);
            s *= sc;
            acc *= sc;
            m = p;
        }
        float w = __expf(p - m);
        s += w;
        acc = fmaf(w, xlj, acc);
    }
    float o = acc / s + bias[head * C + lane];
    out[(size_t)node * HC + head * C + lane] = fmaxf(o, 0.0f);
}

// ---------------- layer-2 aggregation with fused FC head ----------------
__global__ void k_gat_agg2_fc(const float* __restrict__ xl, const float* __restrict__ xr,
                              const float* __restrict__ att, const float* __restrict__ bias,
                              const int* __restrict__ ptr, const int* __restrict__ csrc,
                              const float* __restrict__ Wfc, const float* __restrict__ bfc,
                              float* __restrict__ out) {
    constexpr int C = 64;
    const int node = blockIdx.x * (blockDim.x >> 6) + (threadIdx.x >> 6);
    const int lane = threadIdx.x & 63;
    if (node >= N_NODES) return;

    const float xri = xr[(size_t)node * C + lane];
    const float av  = att[lane];

    float xli = xl[(size_t)node * C + lane];
    float tt = xli + xri;
    tt = tt > 0.0f ? tt : 0.2f * tt;
    float m = wsum(tt * av);
    float s = 1.0f;
    float acc = xli;

    const int e0 = ptr[node], e1 = ptr[node + 1];
    for (int e = e0; e < e1; ++e) {
        int j = csrc[e];
        float xlj = xl[(size_t)j * C + lane];
        float u = xlj + xri;
        u = u > 0.0f ? u : 0.2f * u;
        float p = wsum(u * av);
        if (p > m) {
            float sc = __expf(m - p);
            s *= sc;
            acc *= sc;
            m = p;
        }
        float w = __expf(p - m);
        s += w;
        acc = fmaf(w, xlj, acc);
    }
    float v = fmaxf(acc / s + bias[lane], 0.0f);

    // FC head: out[node][cls] = sum_c v[c] * Wfc[c][cls] + bfc[cls]
    float res = 0.0f;
#pragma unroll
    for (int cls = 0; cls < 10; ++cls) {
        float r = wsum(v * Wfc[lane * 10 + cls]);
        if (lane == cls) res = r + bfc[cls];
    }
    if (lane < 10) out[(size_t)node * 10 + lane] = res;
}

// ---------------- launch ----------------
static inline size_t align256(size_t x) { return (x + 255) & ~(size_t)255; }

extern "C" void kernel_launch(void* const* d_in, const int* in_sizes, int n_in,
                              void* d_out, int out_size, void* d_ws, size_t ws_size,
                              hipStream_t stream) {
    const int N = N_NODES, E = N_EDGES;
    const float* x    = (const float*)d_in[0];
    const int*   ei   = (const int*)d_in[1];
    const float* Wl1  = (const float*)d_in[2];
    const float* Wr1  = (const float*)d_in[3];
    const float* att1 = (const float*)d_in[4];
    const float* b1   = (const float*)d_in[5];
    const float* Wl2  = (const float*)d_in[6];
    const float* Wr2  = (const float*)d_in[7];
    const float* att2 = (const float*)d_in[8];
    const float* b2   = (const float*)d_in[9];
    const float* Wfc  = (const float*)d_in[10];
    const float* bfc  = (const float*)d_in[11];
    float* out = (float*)d_out;

    const int* src = ei;
    const int* dst = ei + E;

    // workspace layout
    char* base = (char*)d_ws;
    size_t off = 0;
    int* ptr  = (int*)(base + off); off = align256(off + (size_t)(N + 1) * 4);
    int* cnt  = (int*)(base + off); off = align256(off + (size_t)N * 4);
    int* bs   = (int*)(base + off); off = align256(off + 256 * 4);
    int* csrc = (int*)(base + off); off = align256(off + (size_t)E * 4);
    float* xl1 = (float*)(base + off); off = align256(off + (size_t)N * 128 * 4);
    float* xr1 = (float*)(base + off); off = align256(off + (size_t)N * 128 * 4);
    float* h1  = (float*)(base + off); off = align256(off + (size_t)N * 128 * 4);
    // layer-2 transforms reuse xl1's region (xl1/xr1 dead after h1 is built)
    float* xl2 = xl1;
    float* xr2 = xl1 + (size_t)N * 64;

    const int nb = (N + 255) / 256;  // 196

    k_zero<<<nb, 256, 0, stream>>>(cnt, N);
    k_hist<<<(E + 255) / 256, 256, 0, stream>>>(dst, cnt, E);
    k_scan_local<<<nb, 256, 0, stream>>>(cnt, ptr, bs, N);
    k_scan_top<<<1, 256, 0, stream>>>(bs, nb);
    k_scan_add<<<nb, 256, 0, stream>>>(ptr, bs, cnt, N, E);
    k_scatter<<<(E + 255) / 256, 256, 0, stream>>>(src, dst, ptr, cnt, csrc, E);

    // layer 1: xl1 = x@Wl1, xr1 = x@Wr1   (N x 128 @ 128 x 128)
    k_gemm2<128, 8><<<N / 8, 256, 0, stream>>>(x, Wl1, Wr1, xl1, xr1);
    // fused GATv2 layer 1 (+bias +relu) -> h1 [N,128]
    k_gat_agg<2><<<(N * 2) / 4, 256, 0, stream>>>(xl1, xr1, att1, b1, ptr, csrc, h1);
    // layer 2: xl2 = h1@Wl2, xr2 = h1@Wr2  (N x 128 @ 128 x 64)
    k_gemm2<64, 4><<<N / 8, 256, 0, stream>>>(h1, Wl2, Wr2, xl2, xr2);
    // fused GATv2 layer 2 (+bias +relu) + FC head -> out [N,10]
    k_gat_agg2_fc<<<N / 4, 256, 0, stream>>>(xl2, xr2, att2, b2, ptr, csrc, Wfc, bfc, out);
}

// Round 2
// 435.192 us; speedup vs baseline: 1.3268x; 1.3268x over previous
//
#include <hip/hip_runtime.h>

#define N_NODES 50000
#define N_EDGES 800000

// ---------------- helpers ----------------
__device__ __forceinline__ float lrelu(float x) { return x > 0.0f ? x : 0.2f * x; }

__device__ __forceinline__ float wsum(float v) {
#pragma unroll
    for (int off = 32; off; off >>= 1) v += __shfl_xor(v, off);
    return v;
}

// two independent 64-lane sums in 9 shuffles; returns {sum t0, sum t1} broadcast
__device__ __forceinline__ float2 wsum2(float t0, float t1) {
    float u = t0 + __shfl_xor(t0, 32);
    float v = t1 + __shfl_xor(t1, 32);
    float w = (threadIdx.x & 32) ? v : u;
#pragma unroll
    for (int off = 16; off; off >>= 1) w += __shfl_xor(w, off);
    return make_float2(__shfl(w, 0), __shfl(w, 32));
}

// ---------------- CSR build ----------------
__global__ void k_zero(int* __restrict__ p, int n) {
    int i = blockIdx.x * blockDim.x + threadIdx.x;
    if (i < n) p[i] = 0;
}

__global__ void k_hist(const int* __restrict__ dst, int* __restrict__ cnt, int E) {
    int e = blockIdx.x * blockDim.x + threadIdx.x;
    if (e < E) atomicAdd(&cnt[dst[e]], 1);
}

__global__ void k_scan_local(const int* __restrict__ cnt, int* __restrict__ ptr,
                             int* __restrict__ bs, int n) {
    __shared__ int tmp[256];
    int t = threadIdx.x;
    int i = blockIdx.x * 256 + t;
    int v = (i < n) ? cnt[i] : 0;
    tmp[t] = v;
    __syncthreads();
    for (int d = 1; d < 256; d <<= 1) {
        int add = (t >= d) ? tmp[t - d] : 0;
        __syncthreads();
        tmp[t] += add;
        __syncthreads();
    }
    if (i < n) ptr[i] = tmp[t] - v;
    if (t == 255) bs[blockIdx.x] = tmp[255];
}

__global__ void k_scan_top(int* __restrict__ bs, int nb) {
    __shared__ int tmp[256];
    int t = threadIdx.x;
    int v = (t < nb) ? bs[t] : 0;
    tmp[t] = v;
    __syncthreads();
    for (int d = 1; d < 256; d <<= 1) {
        int add = (t >= d) ? tmp[t - d] : 0;
        __syncthreads();
        tmp[t] += add;
        __syncthreads();
    }
    if (t < nb) bs[t] = tmp[t] - v;
}

__global__ void k_scan_add(int* __restrict__ ptr, const int* __restrict__ bs,
                           int* __restrict__ cnt, int n, int E) {
    int i = blockIdx.x * 256 + threadIdx.x;
    if (i < n) {
        ptr[i] += bs[blockIdx.x];
        cnt[i] = 0;
    }
    if (i == 0) ptr[n] = E;
}

__global__ void k_scatter(const int* __restrict__ src, const int* __restrict__ dst,
                          const int* __restrict__ ptr, int* __restrict__ cnt,
                          int* __restrict__ csrc, int E) {
    int e = blockIdx.x * blockDim.x + threadIdx.x;
    if (e < E) {
        int i = dst[e];
        int pos = ptr[i] + atomicAdd(&cnt[i], 1);
        csrc[pos] = src[e];
    }
}

// ---------------- dual GEMM: Y1 = X@W1, Y2 = X@W2  (K=128 fixed) ----------------
// IL: write output in head-interleaved layout [N][64][2] (for the H=2 layer-1
// gather path: one float2 per lane feeds both heads).
template <int C, int CPT, bool IL>
__global__ void k_gemm2(const float* __restrict__ X, const float* __restrict__ W1,
                        const float* __restrict__ W2, float* __restrict__ Y1,
                        float* __restrict__ Y2) {
    constexpr int K = 128, KC = 32, TC = 2 * C;
    __shared__ float xs[8][K];
    __shared__ float ws[KC][TC];
    const int t = threadIdx.x;
    const int tx = t & 31, ty = t >> 5;
    const int row = blockIdx.x * 8 + ty;
    {
        int idx = t * 4;
        int r = idx >> 7, c = idx & 127;
        *(float4*)&xs[r][c] = *(const float4*)&X[(size_t)(blockIdx.x * 8 + r) * K + c];
    }
    float acc[CPT] = {};
    const int c0 = tx * CPT;
    for (int kc = 0; kc < K; kc += KC) {
        __syncthreads();
        constexpr int NF4 = KC * TC / 4;
        constexpr int F4PT = NF4 / 256;
#pragma unroll
        for (int i = 0; i < F4PT; ++i) {
            int f = i * 256 + t;
            int k = f / (TC / 4);
            int c4 = (f % (TC / 4)) * 4;
            float4 w;
            if (c4 < C) w = *(const float4*)&W1[(size_t)(kc + k) * C + c4];
            else        w = *(const float4*)&W2[(size_t)(kc + k) * C + (c4 - C)];
            *(float4*)&ws[k][c4] = w;
        }
        __syncthreads();
#pragma unroll 8
        for (int k = 0; k < KC; ++k) {
            float xv = xs[ty][kc + k];
#pragma unroll
            for (int c4 = 0; c4 < CPT; c4 += 4) {
                float4 w = *(float4*)&ws[k][c0 + c4];
                acc[c4 + 0] = fmaf(xv, w.x, acc[c4 + 0]);
                acc[c4 + 1] = fmaf(xv, w.y, acc[c4 + 1]);
                acc[c4 + 2] = fmaf(xv, w.z, acc[c4 + 2]);
                acc[c4 + 3] = fmaf(xv, w.w, acc[c4 + 3]);
            }
        }
    }
    float* Y = (c0 < C) ? Y1 : Y2;
    const int cc = (c0 < C) ? c0 : c0 - C;
    if (IL) {
        // cc in [0,128): head = cc>>6, ch = cc&63 ; CPT|64 so head uniform
        const int h = cc >> 6, ch0 = cc & 63;
#pragma unroll
        for (int i = 0; i < CPT; ++i)
            Y[(size_t)row * 128 + (size_t)(ch0 + i) * 2 + h] = acc[i];
    } else {
#pragma unroll
        for (int c4 = 0; c4 < CPT; c4 += 4) {
            float4 o = make_float4(acc[c4], acc[c4 + 1], acc[c4 + 2], acc[c4 + 3]);
            *(float4*)&Y[(size_t)row * C + cc + c4] = o;
        }
    }
}

// ---------------- layer-1 fused GATv2 aggregation ----------------
// one wave per node, both heads; xl/xr in interleaved [N][64][2] layout;
// output h1 in standard [N][128] (head-major) layout (+bias +relu).
__global__ void k_gat_agg_h2(const float* __restrict__ xl, const float* __restrict__ xr,
                             const float* __restrict__ att, const float* __restrict__ bias,
                             const int* __restrict__ ptr, const int* __restrict__ csrc,
                             float* __restrict__ out) {
    const int node = blockIdx.x * (blockDim.x >> 6) + (threadIdx.x >> 6);
    const int lane = threadIdx.x & 63;
    if (node >= N_NODES) return;
    const size_t nb = (size_t)node * 128;
    const float2 xri = *(const float2*)&xr[nb + 2 * lane];
    const float a0 = att[lane], a1 = att[64 + lane];

    // self loop
    const float2 xs = *(const float2*)&xl[nb + 2 * lane];
    float2 p = wsum2(lrelu(xs.x + xri.x) * a0, lrelu(xs.y + xri.y) * a1);
    float m0 = p.x, m1 = p.y, s0 = 1.0f, s1 = 1.0f;
    float acc0 = xs.x, acc1 = xs.y;

    const int e0 = ptr[node];
    const int deg = ptr[node + 1] - e0;
    for (int base = 0; base < deg; base += 64) {
        const int cl = min(64, deg - base);
        const int idx = (lane < cl) ? csrc[e0 + base + lane] : 0;
        int k = 0;
        for (; k + 4 <= cl; k += 4) {
            const int j0 = __shfl(idx, k + 0), j1 = __shfl(idx, k + 1);
            const int j2 = __shfl(idx, k + 2), j3 = __shfl(idx, k + 3);
            const float2 A = *(const float2*)&xl[(size_t)j0 * 128 + 2 * lane];
            const float2 B = *(const float2*)&xl[(size_t)j1 * 128 + 2 * lane];
            const float2 Cv = *(const float2*)&xl[(size_t)j2 * 128 + 2 * lane];
            const float2 D = *(const float2*)&xl[(size_t)j3 * 128 + 2 * lane];
            const float2 pA = wsum2(lrelu(A.x + xri.x) * a0, lrelu(A.y + xri.y) * a1);
            const float2 pB = wsum2(lrelu(B.x + xri.x) * a0, lrelu(B.y + xri.y) * a1);
            const float2 pC = wsum2(lrelu(Cv.x + xri.x) * a0, lrelu(Cv.y + xri.y) * a1);
            const float2 pD = wsum2(lrelu(D.x + xri.x) * a0, lrelu(D.y + xri.y) * a1);
            // head 0 merge
            {
                const float q = fmaxf(fmaxf(pA.x, pB.x), fmaxf(pC.x, pD.x));
                const float nm = fmaxf(m0, q);
                const float sc = __expf(m0 - nm);
                const float wA = __expf(pA.x - nm), wB = __expf(pB.x - nm);
                const float wC = __expf(pC.x - nm), wD = __expf(pD.x - nm);
                s0 = s0 * sc + ((wA + wB) + (wC + wD));
                acc0 = acc0 * sc + (wA * A.x + wB * B.x) + (wC * Cv.x + wD * D.x);
                m0 = nm;
            }
            // head 1 merge
            {
                const float q = fmaxf(fmaxf(pA.y, pB.y), fmaxf(pC.y, pD.y));
                const float nm = fmaxf(m1, q);
                const float sc = __expf(m1 - nm);
                const float wA = __expf(pA.y - nm), wB = __expf(pB.y - nm);
                const float wC = __expf(pC.y - nm), wD = __expf(pD.y - nm);
                s1 = s1 * sc + ((wA + wB) + (wC + wD));
                acc1 = acc1 * sc + (wA * A.y + wB * B.y) + (wC * Cv.y + wD * D.y);
                m1 = nm;
            }
        }
        for (; k < cl; ++k) {
            const int j = __shfl(idx, k);
            const float2 A = *(const float2*)&xl[(size_t)j * 128 + 2 * lane];
            const float2 pE = wsum2(lrelu(A.x + xri.x) * a0, lrelu(A.y + xri.y) * a1);
            const float nm0 = fmaxf(m0, pE.x), nm1 = fmaxf(m1, pE.y);
            const float sc0 = __expf(m0 - nm0), sc1 = __expf(m1 - nm1);
            const float w0 = __expf(pE.x - nm0), w1 = __expf(pE.y - nm1);
            s0 = s0 * sc0 + w0;
            s1 = s1 * sc1 + w1;
            acc0 = acc0 * sc0 + w0 * A.x;
            acc1 = acc1 * sc1 + w1 * A.y;
            m0 = nm0;
            m1 = nm1;
        }
    }
    out[nb + lane]      = fmaxf(acc0 / s0 + bias[lane], 0.0f);
    out[nb + 64 + lane] = fmaxf(acc1 / s1 + bias[64 + lane], 0.0f);
}

// ---------------- layer-2 aggregation (+bias +relu) with fused FC head ----------------
__global__ void k_gat_agg2_fc(const float* __restrict__ xl, const float* __restrict__ xr,
                              const float* __restrict__ att, const float* __restrict__ bias,
                              const int* __restrict__ ptr, const int* __restrict__ csrc,
                              const float* __restrict__ Wfc, const float* __restrict__ bfc,
                              float* __restrict__ out) {
    const int node = blockIdx.x * (blockDim.x >> 6) + (threadIdx.x >> 6);
    const int lane = threadIdx.x & 63;
    if (node >= N_NODES) return;

    const float xri = xr[(size_t)node * 64 + lane];
    const float av  = att[lane];

    const float xs = xl[(size_t)node * 64 + lane];
    float m = wsum(lrelu(xs + xri) * av);
    float s = 1.0f, acc = xs;

    const int e0 = ptr[node];
    const int deg = ptr[node + 1] - e0;
    for (int base = 0; base < deg; base += 64) {
        const int cl = min(64, deg - base);
        const int idx = (lane < cl) ? csrc[e0 + base + lane] : 0;
        int k = 0;
        for (; k + 4 <= cl; k += 4) {
            const int j0 = __shfl(idx, k + 0), j1 = __shfl(idx, k + 1);
            const int j2 = __shfl(idx, k + 2), j3 = __shfl(idx, k + 3);
            const float A = xl[(size_t)j0 * 64 + lane];
            const float B = xl[(size_t)j1 * 64 + lane];
            const float Cv = xl[(size_t)j2 * 64 + lane];
            const float D = xl[(size_t)j3 * 64 + lane];
            const float2 pAB = wsum2(lrelu(A + xri) * av, lrelu(B + xri) * av);
            const float2 pCD = wsum2(lrelu(Cv + xri) * av, lrelu(D + xri) * av);
            const float q = fmaxf(fmaxf(pAB.x, pAB.y), fmaxf(pCD.x, pCD.y));
            const float nm = fmaxf(m, q);
            const float sc = __expf(m - nm);
            const float wA = __expf(pAB.x - nm), wB = __expf(pAB.y - nm);
            const float wC = __expf(pCD.x - nm), wD = __expf(pCD.y - nm);
            s = s * sc + ((wA + wB) + (wC + wD));
            acc = acc * sc + (wA * A + wB * B) + (wC * Cv + wD * D);
            m = nm;
        }
        for (; k < cl; ++k) {
            const int j = __shfl(idx, k);
            const float A = xl[(size_t)j * 64 + lane];
            const float pE = wsum(lrelu(A + xri) * av);
            const float nm = fmaxf(m, pE);
            const float sc = __expf(m - nm);
            const float w = __expf(pE - nm);
            s = s * sc + w;
            acc = acc * sc + w * A;
            m = nm;
        }
    }
    const float v = fmaxf(acc / s + bias[lane], 0.0f);

    // FC head: out[node][cls] = sum_c v[c] * Wfc[c][cls] + bfc[cls]
    float res = 0.0f;
#pragma unroll
    for (int c2 = 0; c2 < 10; c2 += 2) {
        const float2 r = wsum2(v * Wfc[lane * 10 + c2], v * Wfc[lane * 10 + c2 + 1]);
        if (lane == c2) res = r.x + bfc[c2];
        if (lane == c2 + 1) res = r.y + bfc[c2 + 1];
    }
    if (lane < 10) out[(size_t)node * 10 + lane] = res;
}

// ---------------- launch ----------------
static inline size_t align256(size_t x) { return (x + 255) & ~(size_t)255; }

extern "C" void kernel_launch(void* const* d_in, const int* in_sizes, int n_in,
                              void* d_out, int out_size, void* d_ws, size_t ws_size,
                              hipStream_t stream) {
    const int N = N_NODES, E = N_EDGES;
    const float* x    = (const float*)d_in[0];
    const int*   ei   = (const int*)d_in[1];
    const float* Wl1  = (const float*)d_in[2];
    const float* Wr1  = (const float*)d_in[3];
    const float* att1 = (const float*)d_in[4];
    const float* b1   = (const float*)d_in[5];
    const float* Wl2  = (const float*)d_in[6];
    const float* Wr2  = (const float*)d_in[7];
    const float* att2 = (const float*)d_in[8];
    const float* b2   = (const float*)d_in[9];
    const float* Wfc  = (const float*)d_in[10];
    const float* bfc  = (const float*)d_in[11];
    float* out = (float*)d_out;

    const int* src = ei;
    const int* dst = ei + E;

    char* base = (char*)d_ws;
    size_t off = 0;
    int* ptr  = (int*)(base + off); off = align256(off + (size_t)(N + 1) * 4);
    int* cnt  = (int*)(base + off); off = align256(off + (size_t)N * 4);
    int* bs   = (int*)(base + off); off = align256(off + 256 * 4);
    int* csrc = (int*)(base + off); off = align256(off + (size_t)E * 4);
    float* xl1 = (float*)(base + off); off = align256(off + (size_t)N * 128 * 4);
    float* xr1 = (float*)(base + off); off = align256(off + (size_t)N * 128 * 4);
    float* h1  = (float*)(base + off); off = align256(off + (size_t)N * 128 * 4);
    float* xl2 = xl1;
    float* xr2 = xl1 + (size_t)N * 64;

    const int nb = (N + 255) / 256;

    k_zero<<<nb, 256, 0, stream>>>(cnt, N);
    k_hist<<<(E + 255) / 256, 256, 0, stream>>>(dst, cnt, E);
    k_scan_local<<<nb, 256, 0, stream>>>(cnt, ptr, bs, N);
    k_scan_top<<<1, 256, 0, stream>>>(bs, nb);
    k_scan_add<<<nb, 256, 0, stream>>>(ptr, bs, cnt, N, E);
    k_scatter<<<(E + 255) / 256, 256, 0, stream>>>(src, dst, ptr, cnt, csrc, E);

    // layer 1: xl1/xr1 in interleaved [N][64][2] layout
    k_gemm2<128, 8, true><<<N / 8, 256, 0, stream>>>(x, Wl1, Wr1, xl1, xr1);
    k_gat_agg_h2<<<(N + 3) / 4, 256, 0, stream>>>(xl1, xr1, att1, b1, ptr, csrc, h1);
    // layer 2: standard layout
    k_gemm2<64, 4, false><<<N / 8, 256, 0, stream>>>(h1, Wl2, Wr2, xl2, xr2);
    k_gat_agg2_fc<<<N / 4, 256, 0, stream>>>(xl2, xr2, att2, b2, ptr, csrc, Wfc, bfc, out);
}

// Round 3
// 351.948 us; speedup vs baseline: 1.6406x; 1.2365x over previous
//
#include <hip/hip_runtime.h>

#define N_NODES 50000
#define N_EDGES 800000

// ---------------- helpers ----------------
__device__ __forceinline__ float lrelu(float x) { return x > 0.0f ? x : 0.2f * x; }

__device__ __forceinline__ float wsum(float v) {
#pragma unroll
    for (int off = 32; off; off >>= 1) v += __shfl_xor(v, off);
    return v;
}

// two independent 64-lane sums in 9 shuffles; returns {sum t0, sum t1} broadcast
__device__ __forceinline__ float2 wsum2(float t0, float t1) {
    float u = t0 + __shfl_xor(t0, 32);
    float v = t1 + __shfl_xor(t1, 32);
    float w = (threadIdx.x & 32) ? v : u;
#pragma unroll
    for (int off = 16; off; off >>= 1) w += __shfl_xor(w, off);
    return make_float2(__shfl(w, 0), __shfl(w, 32));
}

// ---------------- CSR build ----------------
__global__ void k_zero(int* __restrict__ p, int n) {
    int i = blockIdx.x * blockDim.x + threadIdx.x;
    if (i < n) p[i] = 0;
}

__global__ void k_hist(const int* __restrict__ dst, int* __restrict__ cnt, int E) {
    int e = blockIdx.x * blockDim.x + threadIdx.x;
    if (e < E) atomicAdd(&cnt[dst[e]], 1);
}

__global__ void k_scan_local(const int* __restrict__ cnt, int* __restrict__ ptr,
                             int* __restrict__ bs, int n) {
    __shared__ int tmp[256];
    int t = threadIdx.x;
    int i = blockIdx.x * 256 + t;
    int v = (i < n) ? cnt[i] : 0;
    tmp[t] = v;
    __syncthreads();
    for (int d = 1; d < 256; d <<= 1) {
        int add = (t >= d) ? tmp[t - d] : 0;
        __syncthreads();
        tmp[t] += add;
        __syncthreads();
    }
    if (i < n) ptr[i] = tmp[t] - v;
    if (t == 255) bs[blockIdx.x] = tmp[255];
}

__global__ void k_scan_top(int* __restrict__ bs, int nb) {
    __shared__ int tmp[256];
    int t = threadIdx.x;
    int v = (t < nb) ? bs[t] : 0;
    tmp[t] = v;
    __syncthreads();
    for (int d = 1; d < 256; d <<= 1) {
        int add = (t >= d) ? tmp[t - d] : 0;
        __syncthreads();
        tmp[t] += add;
        __syncthreads();
    }
    if (t < nb) bs[t] = tmp[t] - v;
}

__global__ void k_scan_add(int* __restrict__ ptr, const int* __restrict__ bs,
                           int* __restrict__ cnt, int n, int E) {
    int i = blockIdx.x * 256 + threadIdx.x;
    if (i < n) {
        ptr[i] += bs[blockIdx.x];
        cnt[i] = 0;
    }
    if (i == 0) ptr[n] = E;
}

__global__ void k_scatter(const int* __restrict__ src, const int* __restrict__ dst,
                          const int* __restrict__ ptr, int* __restrict__ cnt,
                          int* __restrict__ csrc, int E) {
    int e = blockIdx.x * blockDim.x + threadIdx.x;
    if (e < E) {
        int i = dst[e];
        int pos = ptr[i] + atomicAdd(&cnt[i], 1);
        csrc[pos] = src[e];
    }
}

// ---------------- GEMM v2: 128x128 register-tiled, K=128 ----------------
// 256 threads (tx=t&15, ty=t>>4); thread computes 8x8 outputs:
//   rows  row0 + ty*4 + {0..3} and +64,  cols tx*4 + {0..3} and +64 (two 64-col halves)
// IL=true  (layer 1): blockIdx.y selects W (Wl or Wr); halfA = W cols 0..63 (head0),
//   halfB = W cols 64..127 (head1); output head-interleaved [N][64][2] via float4 pairs.
// IL=false (layer 2): halfA = W0 (64 cols) -> Y0, halfB = W1 -> Y1, both [N][64].
template <bool IL>
__global__ __launch_bounds__(256)
void k_gemm_v2(const float* __restrict__ X, int nrows,
               const float* __restrict__ W0, const float* __restrict__ W1,
               float* __restrict__ Y0, float* __restrict__ Y1) {
    constexpr int BK = 32;
    __shared__ float xsT[BK][132];  // transposed X tile; pad 132 -> 16B-aligned rows
    __shared__ float ws[BK][128];   // [k][c]: c<64 halfA, c>=64 halfB
    const int t = threadIdx.x;
    const int tx = t & 15, ty = t >> 4;
    const int row0 = blockIdx.x * 128;

    const float* Wa;
    const float* Wb;
    int ldw;
    float* Ya;
    float* Yb;
    if (IL) {
        const float* W = blockIdx.y ? W1 : W0;
        Wa = W;
        Wb = W + 64;
        ldw = 128;
        Ya = blockIdx.y ? Y1 : Y0;
        Yb = nullptr;
    } else {
        Wa = W0;
        Wb = W1;
        ldw = 64;
        Ya = Y0;
        Yb = Y1;
    }

    float acc[8][8] = {};

    for (int kc = 0; kc < 128; kc += BK) {
        __syncthreads();
        // stage X^T: thread owns row (t&127), k-quarters (t>>7)+2i
        {
            const int row = t & 127;
            const int rg = min(row0 + row, nrows - 1);
            const float* xr = &X[(size_t)rg * 128 + kc];
#pragma unroll
            for (int i = 0; i < 4; ++i) {
                const int k0 = ((t >> 7) + 2 * i) * 4;
                float4 v = *(const float4*)&xr[k0];
                xsT[k0 + 0][row] = v.x;
                xsT[k0 + 1][row] = v.y;
                xsT[k0 + 2][row] = v.z;
                xsT[k0 + 3][row] = v.w;
            }
        }
        // stage W: 4096 floats = 1024 float4 / 256 threads
#pragma unroll
        for (int i = 0; i < 4; ++i) {
            const int f4 = t + i * 256;
            const int k = f4 >> 5;
            const int c4 = (f4 & 31) * 4;
            const float* Wsrc = (c4 < 64) ? Wa : Wb;
            const int cc = (c4 < 64) ? c4 : c4 - 64;
            *(float4*)&ws[k][c4] = *(const float4*)&Wsrc[(size_t)(kc + k) * ldw + cc];
        }
        __syncthreads();
#pragma unroll 4
        for (int k = 0; k < BK; ++k) {
            const float4 a0 = *(const float4*)&xsT[k][ty * 4];
            const float4 a1 = *(const float4*)&xsT[k][ty * 4 + 64];
            const float4 b0 = *(const float4*)&ws[k][tx * 4];
            const float4 b1 = *(const float4*)&ws[k][tx * 4 + 64];
            const float ar[8] = {a0.x, a0.y, a0.z, a0.w, a1.x, a1.y, a1.z, a1.w};
            const float br[8] = {b0.x, b0.y, b0.z, b0.w, b1.x, b1.y, b1.z, b1.w};
#pragma unroll
            for (int i = 0; i < 8; ++i)
#pragma unroll
                for (int j = 0; j < 8; ++j)
                    acc[i][j] = fmaf(ar[i], br[j], acc[i][j]);
        }
    }

#pragma unroll
    for (int i = 0; i < 8; ++i) {
        const int r = row0 + ty * 4 + (i & 3) + (i >> 2) * 64;
        if (r >= nrows) continue;
        if (IL) {
            // head-interleaved: pos (ch)*2 + head, ch = tx*4+j
            float4 o0 = make_float4(acc[i][0], acc[i][4], acc[i][1], acc[i][5]);
            float4 o1 = make_float4(acc[i][2], acc[i][6], acc[i][3], acc[i][7]);
            *(float4*)&Ya[(size_t)r * 128 + tx * 8] = o0;
            *(float4*)&Ya[(size_t)r * 128 + tx * 8 + 4] = o1;
        } else {
            *(float4*)&Ya[(size_t)r * 64 + tx * 4] =
                make_float4(acc[i][0], acc[i][1], acc[i][2], acc[i][3]);
            *(float4*)&Yb[(size_t)r * 64 + tx * 4] =
                make_float4(acc[i][4], acc[i][5], acc[i][6], acc[i][7]);
        }
    }
}

// ---------------- layer-1 fused GATv2 aggregation ----------------
__global__ void k_gat_agg_h2(const float* __restrict__ xl, const float* __restrict__ xr,
                             const float* __restrict__ att, const float* __restrict__ bias,
                             const int* __restrict__ ptr, const int* __restrict__ csrc,
                             float* __restrict__ out) {
    const int node = blockIdx.x * (blockDim.x >> 6) + (threadIdx.x >> 6);
    const int lane = threadIdx.x & 63;
    if (node >= N_NODES) return;
    const size_t nb = (size_t)node * 128;
    const float2 xri = *(const float2*)&xr[nb + 2 * lane];
    const float a0 = att[lane], a1 = att[64 + lane];

    const float2 xs = *(const float2*)&xl[nb + 2 * lane];
    float2 p = wsum2(lrelu(xs.x + xri.x) * a0, lrelu(xs.y + xri.y) * a1);
    float m0 = p.x, m1 = p.y, s0 = 1.0f, s1 = 1.0f;
    float acc0 = xs.x, acc1 = xs.y;

    const int e0 = ptr[node];
    const int deg = ptr[node + 1] - e0;
    for (int base = 0; base < deg; base += 64) {
        const int cl = min(64, deg - base);
        const int idx = (lane < cl) ? csrc[e0 + base + lane] : 0;
        int k = 0;
        for (; k + 4 <= cl; k += 4) {
            const int j0 = __shfl(idx, k + 0), j1 = __shfl(idx, k + 1);
            const int j2 = __shfl(idx, k + 2), j3 = __shfl(idx, k + 3);
            const float2 A = *(const float2*)&xl[(size_t)j0 * 128 + 2 * lane];
            const float2 B = *(const float2*)&xl[(size_t)j1 * 128 + 2 * lane];
            const float2 Cv = *(const float2*)&xl[(size_t)j2 * 128 + 2 * lane];
            const float2 D = *(const float2*)&xl[(size_t)j3 * 128 + 2 * lane];
            const float2 pA = wsum2(lrelu(A.x + xri.x) * a0, lrelu(A.y + xri.y) * a1);
            const float2 pB = wsum2(lrelu(B.x + xri.x) * a0, lrelu(B.y + xri.y) * a1);
            const float2 pC = wsum2(lrelu(Cv.x + xri.x) * a0, lrelu(Cv.y + xri.y) * a1);
            const float2 pD = wsum2(lrelu(D.x + xri.x) * a0, lrelu(D.y + xri.y) * a1);
            {
                const float q = fmaxf(fmaxf(pA.x, pB.x), fmaxf(pC.x, pD.x));
                const float nm = fmaxf(m0, q);
                const float sc = __expf(m0 - nm);
                const float wA = __expf(pA.x - nm), wB = __expf(pB.x - nm);
                const float wC = __expf(pC.x - nm), wD = __expf(pD.x - nm);
                s0 = s0 * sc + ((wA + wB) + (wC + wD));
                acc0 = acc0 * sc + (wA * A.x + wB * B.x) + (wC * Cv.x + wD * D.x);
                m0 = nm;
            }
            {
                const float q = fmaxf(fmaxf(pA.y, pB.y), fmaxf(pC.y, pD.y));
                const float nm = fmaxf(m1, q);
                const float sc = __expf(m1 - nm);
                const float wA = __expf(pA.y - nm), wB = __expf(pB.y - nm);
                const float wC = __expf(pC.y - nm), wD = __expf(pD.y - nm);
                s1 = s1 * sc + ((wA + wB) + (wC + wD));
                acc1 = acc1 * sc + (wA * A.y + wB * B.y) + (wC * Cv.y + wD * D.y);
                m1 = nm;
            }
        }
        for (; k < cl; ++k) {
            const int j = __shfl(idx, k);
            const float2 A = *(const float2*)&xl[(size_t)j * 128 + 2 * lane];
            const float2 pE = wsum2(lrelu(A.x + xri.x) * a0, lrelu(A.y + xri.y) * a1);
            const float nm0 = fmaxf(m0, pE.x), nm1 = fmaxf(m1, pE.y);
            const float sc0 = __expf(m0 - nm0), sc1 = __expf(m1 - nm1);
            const float w0 = __expf(pE.x - nm0), w1 = __expf(pE.y - nm1);
            s0 = s0 * sc0 + w0;
            s1 = s1 * sc1 + w1;
            acc0 = acc0 * sc0 + w0 * A.x;
            acc1 = acc1 * sc1 + w1 * A.y;
            m0 = nm0;
            m1 = nm1;
        }
    }
    out[nb + lane]      = fmaxf(acc0 / s0 + bias[lane], 0.0f);
    out[nb + 64 + lane] = fmaxf(acc1 / s1 + bias[64 + lane], 0.0f);
}

// ---------------- layer-2 aggregation (+bias +relu) with fused FC head ----------------
__global__ void k_gat_agg2_fc(const float* __restrict__ xl, const float* __restrict__ xr,
                              const float* __restrict__ att, const float* __restrict__ bias,
                              const int* __restrict__ ptr, const int* __restrict__ csrc,
                              const float* __restrict__ Wfc, const float* __restrict__ bfc,
                              float* __restrict__ out) {
    const int node = blockIdx.x * (blockDim.x >> 6) + (threadIdx.x >> 6);
    const int lane = threadIdx.x & 63;
    if (node >= N_NODES) return;

    const float xri = xr[(size_t)node * 64 + lane];
    const float av  = att[lane];

    const float xs = xl[(size_t)node * 64 + lane];
    float m = wsum(lrelu(xs + xri) * av);
    float s = 1.0f, acc = xs;

    const int e0 = ptr[node];
    const int deg = ptr[node + 1] - e0;
    for (int base = 0; base < deg; base += 64) {
        const int cl = min(64, deg - base);
        const int idx = (lane < cl) ? csrc[e0 + base + lane] : 0;
        int k = 0;
        for (; k + 4 <= cl; k += 4) {
            const int j0 = __shfl(idx, k + 0), j1 = __shfl(idx, k + 1);
            const int j2 = __shfl(idx, k + 2), j3 = __shfl(idx, k + 3);
            const float A = xl[(size_t)j0 * 64 + lane];
            const float B = xl[(size_t)j1 * 64 + lane];
            const float Cv = xl[(size_t)j2 * 64 + lane];
            const float D = xl[(size_t)j3 * 64 + lane];
            const float2 pAB = wsum2(lrelu(A + xri) * av, lrelu(B + xri) * av);
            const float2 pCD = wsum2(lrelu(Cv + xri) * av, lrelu(D + xri) * av);
            const float q = fmaxf(fmaxf(pAB.x, pAB.y), fmaxf(pCD.x, pCD.y));
            const float nm = fmaxf(m, q);
            const float sc = __expf(m - nm);
            const float wA = __expf(pAB.x - nm), wB = __expf(pAB.y - nm);
            const float wC = __expf(pCD.x - nm), wD = __expf(pCD.y - nm);
            s = s * sc + ((wA + wB) + (wC + wD));
            acc = acc * sc + (wA * A + wB * B) + (wC * Cv + wD * D);
            m = nm;
        }
        for (; k < cl; ++k) {
            const int j = __shfl(idx, k);
            const float A = xl[(size_t)j * 64 + lane];
            const float pE = wsum(lrelu(A + xri) * av);
            const float nm = fmaxf(m, pE);
            const float sc = __expf(m - nm);
            const float w = __expf(pE - nm);
            s = s * sc + w;
            acc = acc * sc + w * A;
            m = nm;
        }
    }
    const float v = fmaxf(acc / s + bias[lane], 0.0f);

    float res = 0.0f;
#pragma unroll
    for (int c2 = 0; c2 < 10; c2 += 2) {
        const float2 r = wsum2(v * Wfc[lane * 10 + c2], v * Wfc[lane * 10 + c2 + 1]);
        if (lane == c2) res = r.x + bfc[c2];
        if (lane == c2 + 1) res = r.y + bfc[c2 + 1];
    }
    if (lane < 10) out[(size_t)node * 10 + lane] = res;
}

// ---------------- launch ----------------
static inline size_t align256(size_t x) { return (x + 255) & ~(size_t)255; }

extern "C" void kernel_launch(void* const* d_in, const int* in_sizes, int n_in,
                              void* d_out, int out_size, void* d_ws, size_t ws_size,
                              hipStream_t stream) {
    const int N = N_NODES, E = N_EDGES;
    const float* x    = (const float*)d_in[0];
    const int*   ei   = (const int*)d_in[1];
    const float* Wl1  = (const float*)d_in[2];
    const float* Wr1  = (const float*)d_in[3];
    const float* att1 = (const float*)d_in[4];
    const float* b1   = (const float*)d_in[5];
    const float* Wl2  = (const float*)d_in[6];
    const float* Wr2  = (const float*)d_in[7];
    const float* att2 = (const float*)d_in[8];
    const float* b2   = (const float*)d_in[9];
    const float* Wfc  = (const float*)d_in[10];
    const float* bfc  = (const float*)d_in[11];
    float* out = (float*)d_out;

    const int* src = ei;
    const int* dst = ei + E;

    char* base = (char*)d_ws;
    size_t off = 0;
    int* ptr  = (int*)(base + off); off = align256(off + (size_t)(N + 1) * 4);
    int* cnt  = (int*)(base + off); off = align256(off + (size_t)N * 4);
    int* bs   = (int*)(base + off); off = align256(off + 256 * 4);
    int* csrc = (int*)(base + off); off = align256(off + (size_t)E * 4);
    float* xl1 = (float*)(base + off); off = align256(off + (size_t)N * 128 * 4);
    float* xr1 = (float*)(base + off); off = align256(off + (size_t)N * 128 * 4);
    float* h1  = (float*)(base + off); off = align256(off + (size_t)N * 128 * 4);
    float* xl2 = xl1;
    float* xr2 = xl1 + (size_t)N * 64;

    const int nb = (N + 255) / 256;
    const int ngb = (N + 127) / 128;  // 391

    k_zero<<<nb, 256, 0, stream>>>(cnt, N);
    k_hist<<<(E + 255) / 256, 256, 0, stream>>>(dst, cnt, E);
    k_scan_local<<<nb, 256, 0, stream>>>(cnt, ptr, bs, N);
    k_scan_top<<<1, 256, 0, stream>>>(bs, nb);
    k_scan_add<<<nb, 256, 0, stream>>>(ptr, bs, cnt, N, E);
    k_scatter<<<(E + 255) / 256, 256, 0, stream>>>(src, dst, ptr, cnt, csrc, E);

    // layer 1: xl1/xr1 head-interleaved [N][64][2]
    k_gemm_v2<true><<<dim3(ngb, 2), 256, 0, stream>>>(x, N, Wl1, Wr1, xl1, xr1);
    k_gat_agg_h2<<<(N + 3) / 4, 256, 0, stream>>>(xl1, xr1, att1, b1, ptr, csrc, h1);
    // layer 2: standard [N][64] x2
    k_gemm_v2<false><<<dim3(ngb, 1), 256, 0, stream>>>(h1, N, Wl2, Wr2, xl2, xr2);
    k_gat_agg2_fc<<<N / 4, 256, 0, stream>>>(xl2, xr2, att2, b2, ptr, csrc, Wfc, bfc, out);
}

// Round 4
// 292.409 us; speedup vs baseline: 1.9746x; 1.2036x over previous
//
#include <hip/hip_runtime.h>

#define N_NODES 50000
#define N_EDGES 800000

// DPP quad_perm controls: xor1 = [1,0,3,2] = 0xB1, xor2 = [2,3,0,1] = 0x4E
#define QX1 0xB1
#define QX2 0x4E

template <int CTRL>
__device__ __forceinline__ float dpp_add(float x) {
    int xi = __float_as_int(x);
    int yi = __builtin_amdgcn_update_dpp(xi, xi, CTRL, 0xF, 0xF, false);
    return x + __int_as_float(yi);
}
template <int CTRL>
__device__ __forceinline__ float dpp_max(float x) {
    int xi = __float_as_int(x);
    int yi = __builtin_amdgcn_update_dpp(xi, xi, CTRL, 0xF, 0xF, false);
    return fmaxf(x, __int_as_float(yi));
}

__device__ __forceinline__ float lrelu(float x) { return fmaxf(x, 0.2f * x); }

__device__ __forceinline__ float wsum(float v) {
#pragma unroll
    for (int off = 32; off; off >>= 1) v += __shfl_xor(v, off);
    return v;
}

__device__ __forceinline__ float2 wsum2(float t0, float t1) {
    float u = t0 + __shfl_xor(t0, 32);
    float v = t1 + __shfl_xor(t1, 32);
    float w = (threadIdx.x & 32) ? v : u;
#pragma unroll
    for (int off = 16; off; off >>= 1) w += __shfl_xor(w, off);
    return make_float2(__shfl(w, 0), __shfl(w, 32));
}

// ---------------- CSR build ----------------
__global__ void k_zero(int* __restrict__ p, int n) {
    int i = blockIdx.x * blockDim.x + threadIdx.x;
    if (i < n) p[i] = 0;
}

__global__ void k_hist(const int* __restrict__ dst, int* __restrict__ cnt, int E) {
    int e = blockIdx.x * blockDim.x + threadIdx.x;
    if (e < E) atomicAdd(&cnt[dst[e]], 1);
}

__global__ void k_scan_local(const int* __restrict__ cnt, int* __restrict__ ptr,
                             int* __restrict__ bs, int n) {
    __shared__ int tmp[256];
    int t = threadIdx.x;
    int i = blockIdx.x * 256 + t;
    int v = (i < n) ? cnt[i] : 0;
    tmp[t] = v;
    __syncthreads();
    for (int d = 1; d < 256; d <<= 1) {
        int add = (t >= d) ? tmp[t - d] : 0;
        __syncthreads();
        tmp[t] += add;
        __syncthreads();
    }
    if (i < n) ptr[i] = tmp[t] - v;
    if (t == 255) bs[blockIdx.x] = tmp[255];
}

__global__ void k_scan_top(int* __restrict__ bs, int nb) {
    __shared__ int tmp[256];
    int t = threadIdx.x;
    int v = (t < nb) ? bs[t] : 0;
    tmp[t] = v;
    __syncthreads();
    for (int d = 1; d < 256; d <<= 1) {
        int add = (t >= d) ? tmp[t - d] : 0;
        __syncthreads();
        tmp[t] += add;
        __syncthreads();
    }
    if (t < nb) bs[t] = tmp[t] - v;
}

__global__ void k_scan_add(int* __restrict__ ptr, const int* __restrict__ bs,
                           int* __restrict__ cnt, int n, int E) {
    int i = blockIdx.x * 256 + threadIdx.x;
    if (i < n) {
        ptr[i] += bs[blockIdx.x];
        cnt[i] = 0;
    }
    if (i == 0) ptr[n] = E;
}

__global__ void k_scatter(const int* __restrict__ src, const int* __restrict__ dst,
                          const int* __restrict__ ptr, int* __restrict__ cnt,
                          int* __restrict__ csrc, int E) {
    int e = blockIdx.x * blockDim.x + threadIdx.x;
    if (e < E) {
        int i = dst[e];
        int pos = ptr[i] + atomicAdd(&cnt[i], 1);
        csrc[pos] = src[e];
    }
}

// ---------------- GEMM: 128x128 register-tiled, K=128 ----------------
// WIDE=true (layer 1): blockIdx.y selects (W,Y) pair; W has 128 cols (halves 0-63 / 64-127),
//   Y is [N][128]. WIDE=false (layer 2): halfA = W0 -> Y0, halfB = W1 -> Y1, both [N][64].
template <bool WIDE>
__global__ __launch_bounds__(256)
void k_gemm_v2(const float* __restrict__ X, int nrows,
               const float* __restrict__ W0, const float* __restrict__ W1,
               float* __restrict__ Y0, float* __restrict__ Y1) {
    constexpr int BK = 32;
    __shared__ float xsT[BK][132];
    __shared__ float ws[BK][128];
    const int t = threadIdx.x;
    const int tx = t & 15, ty = t >> 4;
    const int row0 = blockIdx.x * 128;

    const float* Wa;
    const float* Wb;
    int ldw;
    float* Ya;
    float* Yb;
    if (WIDE) {
        const float* W = blockIdx.y ? W1 : W0;
        Wa = W;
        Wb = W + 64;
        ldw = 128;
        Ya = blockIdx.y ? Y1 : Y0;
        Yb = nullptr;
    } else {
        Wa = W0;
        Wb = W1;
        ldw = 64;
        Ya = Y0;
        Yb = Y1;
    }

    float acc[8][8] = {};

    for (int kc = 0; kc < 128; kc += BK) {
        __syncthreads();
        {
            const int row = t & 127;
            const int rg = min(row0 + row, nrows - 1);
            const float* xr = &X[(size_t)rg * 128 + kc];
#pragma unroll
            for (int i = 0; i < 4; ++i) {
                const int k0 = ((t >> 7) + 2 * i) * 4;
                float4 v = *(const float4*)&xr[k0];
                xsT[k0 + 0][row] = v.x;
                xsT[k0 + 1][row] = v.y;
                xsT[k0 + 2][row] = v.z;
                xsT[k0 + 3][row] = v.w;
            }
        }
#pragma unroll
        for (int i = 0; i < 4; ++i) {
            const int f4 = t + i * 256;
            const int k = f4 >> 5;
            const int c4 = (f4 & 31) * 4;
            const float* Wsrc = (c4 < 64) ? Wa : Wb;
            const int cc = (c4 < 64) ? c4 : c4 - 64;
            *(float4*)&ws[k][c4] = *(const float4*)&Wsrc[(size_t)(kc + k) * ldw + cc];
        }
        __syncthreads();
#pragma unroll 4
        for (int k = 0; k < BK; ++k) {
            const float4 a0 = *(const float4*)&xsT[k][ty * 4];
            const float4 a1 = *(const float4*)&xsT[k][ty * 4 + 64];
            const float4 b0 = *(const float4*)&ws[k][tx * 4];
            const float4 b1 = *(const float4*)&ws[k][tx * 4 + 64];
            const float ar[8] = {a0.x, a0.y, a0.z, a0.w, a1.x, a1.y, a1.z, a1.w};
            const float br[8] = {b0.x, b0.y, b0.z, b0.w, b1.x, b1.y, b1.z, b1.w};
#pragma unroll
            for (int i = 0; i < 8; ++i)
#pragma unroll
                for (int j = 0; j < 8; ++j)
                    acc[i][j] = fmaf(ar[i], br[j], acc[i][j]);
        }
    }

#pragma unroll
    for (int i = 0; i < 8; ++i) {
        const int r = row0 + ty * 4 + (i & 3) + (i >> 2) * 64;
        if (r >= nrows) continue;
        if (WIDE) {
            *(float4*)&Ya[(size_t)r * 128 + tx * 4] =
                make_float4(acc[i][0], acc[i][1], acc[i][2], acc[i][3]);
            *(float4*)&Ya[(size_t)r * 128 + 64 + tx * 4] =
                make_float4(acc[i][4], acc[i][5], acc[i][6], acc[i][7]);
        } else {
            *(float4*)&Ya[(size_t)r * 64 + tx * 4] =
                make_float4(acc[i][0], acc[i][1], acc[i][2], acc[i][3]);
            *(float4*)&Yb[(size_t)r * 64 + tx * 4] =
                make_float4(acc[i][4], acc[i][5], acc[i][6], acc[i][7]);
        }
    }
}

// ---------------- layer-1 fused GATv2 aggregation (standard [N][128] layout) ----------------
// lane l: channels 2l,2l+1 of head (l>>5). 4-edge packed-tree blocks, branch-free tail.
__global__ __launch_bounds__(256) void k_agg1(
    const float* __restrict__ xl, const float* __restrict__ xr,
    const float* __restrict__ att, const float* __restrict__ bias,
    const int* __restrict__ ptr, const int* __restrict__ csrc,
    float* __restrict__ out) {
    const int node = blockIdx.x * 4 + (threadIdx.x >> 6);
    const int lane = threadIdx.x & 63;
    if (node >= N_NODES) return;
    const size_t nb = (size_t)node * 128;
    const float2 xri = *(const float2*)&xr[nb + 2 * lane];
    const float2 atv = *(const float2*)&att[2 * lane];
    const int lane3 = lane & 3;
    // bpermute byte-addresses for w broadcast (edge e of my head-half)
    const int ba0 = ((lane & 32) << 2);
    const int ba1 = ba0 + 4, ba2 = ba0 + 8, ba3 = ba0 + 12;

    // self loop
    const float2 xs = *(const float2*)&xl[nb + 2 * lane];
    float m, s, acc0, acc1;
    {
        float t = lrelu(xs.x + xri.x) * atv.x + lrelu(xs.y + xri.y) * atv.y;
        t = dpp_add<QX1>(t);
        t = dpp_add<QX2>(t);
        t += __shfl_xor(t, 4);
        t += __shfl_xor(t, 8);
        t += __shfl_xor(t, 16);
        m = t;
        s = 1.0f;
        acc0 = xs.x;
        acc1 = xs.y;
    }

    const int e0 = ptr[node];
    const int deg = ptr[node + 1] - e0;
    for (int base = 0; base < deg; base += 64) {
        const int nv = deg - base;
        const int idx = csrc[e0 + base + min(lane, nv - 1)];
        const int nb4 = min(nv, 64);
        for (int k = 0; k < nb4; k += 4) {
            const int j0 = __builtin_amdgcn_readlane(idx, k);
            const int j1 = __builtin_amdgcn_readlane(idx, min(k + 1, nb4 - 1));
            const int j2 = __builtin_amdgcn_readlane(idx, min(k + 2, nb4 - 1));
            const int j3 = __builtin_amdgcn_readlane(idx, min(k + 3, nb4 - 1));
            const float2 A0 = *(const float2*)&xl[(size_t)j0 * 128 + 2 * lane];
            const float2 A1 = *(const float2*)&xl[(size_t)j1 * 128 + 2 * lane];
            const float2 A2 = *(const float2*)&xl[(size_t)j2 * 128 + 2 * lane];
            const float2 A3 = *(const float2*)&xl[(size_t)j3 * 128 + 2 * lane];
            float t0 = lrelu(A0.x + xri.x) * atv.x + lrelu(A0.y + xri.y) * atv.y;
            float t1 = lrelu(A1.x + xri.x) * atv.x + lrelu(A1.y + xri.y) * atv.y;
            float t2 = lrelu(A2.x + xri.x) * atv.x + lrelu(A2.y + xri.y) * atv.y;
            float t3 = lrelu(A3.x + xri.x) * atv.x + lrelu(A3.y + xri.y) * atv.y;
            // packed tree reduce: edges -> bits 0,1 of lane; channel sum over bits 2..4
            t0 = dpp_add<QX1>(t0);
            t1 = dpp_add<QX1>(t1);
            t2 = dpp_add<QX1>(t2);
            t3 = dpp_add<QX1>(t3);
            float a = (lane & 1) ? t1 : t0;
            float b = (lane & 1) ? t3 : t2;
            a = dpp_add<QX2>(a);
            b = dpp_add<QX2>(b);
            float p = (lane & 2) ? b : a;
            p += __shfl_xor(p, 4);
            p += __shfl_xor(p, 8);
            p += __shfl_xor(p, 16);
            // mask invalid edges (branch-free tail)
            p = (k + lane3 < nb4) ? p : -1e30f;
            // online-softmax merge (per head-half, packed)
            float q = dpp_max<QX1>(p);
            q = dpp_max<QX2>(q);
            const float nm = fmaxf(m, q);
            const float sc = __expf(m - nm);
            const float w = __expf(p - nm);
            float sw = dpp_add<QX1>(w);
            sw = dpp_add<QX2>(sw);
            s = fmaf(s, sc, sw);
            m = nm;
            const int wi = __float_as_int(w);
            const float w0 = __int_as_float(__builtin_amdgcn_ds_bpermute(ba0, wi));
            const float w1 = __int_as_float(__builtin_amdgcn_ds_bpermute(ba1, wi));
            const float w2 = __int_as_float(__builtin_amdgcn_ds_bpermute(ba2, wi));
            const float w3 = __int_as_float(__builtin_amdgcn_ds_bpermute(ba3, wi));
            acc0 = fmaf(w3, A3.x, fmaf(w2, A2.x, fmaf(w1, A1.x, fmaf(w0, A0.x, acc0 * sc))));
            acc1 = fmaf(w3, A3.y, fmaf(w2, A2.y, fmaf(w1, A1.y, fmaf(w0, A0.y, acc1 * sc))));
        }
    }
    const float inv = 1.0f / s;
    float2 o;
    o.x = fmaxf(fmaf(acc0, inv, bias[2 * lane]), 0.0f);
    o.y = fmaxf(fmaf(acc1, inv, bias[2 * lane + 1]), 0.0f);
    *(float2*)&out[nb + 2 * lane] = o;
}

// ---------------- layer-2 aggregation + fused FC head ----------------
// lane = channel (64), 1 head. 4-edge packed blocks; w broadcast via readlane (SALU).
__global__ __launch_bounds__(256) void k_agg2_fc(
    const float* __restrict__ xl, const float* __restrict__ xr,
    const float* __restrict__ att, const float* __restrict__ bias,
    const int* __restrict__ ptr, const int* __restrict__ csrc,
    const float* __restrict__ Wfc, const float* __restrict__ bfc,
    float* __restrict__ out) {
    const int node = blockIdx.x * 4 + (threadIdx.x >> 6);
    const int lane = threadIdx.x & 63;
    if (node >= N_NODES) return;
    const float xri = xr[(size_t)node * 64 + lane];
    const float av = att[lane];
    const int lane3 = lane & 3;

    const float xs = xl[(size_t)node * 64 + lane];
    float m, s, acc;
    {
        float t = lrelu(xs + xri) * av;
        t = dpp_add<QX1>(t);
        t = dpp_add<QX2>(t);
        t += __shfl_xor(t, 4);
        t += __shfl_xor(t, 8);
        t += __shfl_xor(t, 16);
        t += __shfl_xor(t, 32);
        m = t;
        s = 1.0f;
        acc = xs;
    }

    const int e0 = ptr[node];
    const int deg = ptr[node + 1] - e0;
    for (int base = 0; base < deg; base += 64) {
        const int nv = deg - base;
        const int idx = csrc[e0 + base + min(lane, nv - 1)];
        const int nb4 = min(nv, 64);
        for (int k = 0; k < nb4; k += 4) {
            const int j0 = __builtin_amdgcn_readlane(idx, k);
            const int j1 = __builtin_amdgcn_readlane(idx, min(k + 1, nb4 - 1));
            const int j2 = __builtin_amdgcn_readlane(idx, min(k + 2, nb4 - 1));
            const int j3 = __builtin_amdgcn_readlane(idx, min(k + 3, nb4 - 1));
            const float A0 = xl[(size_t)j0 * 64 + lane];
            const float A1 = xl[(size_t)j1 * 64 + lane];
            const float A2 = xl[(size_t)j2 * 64 + lane];
            const float A3 = xl[(size_t)j3 * 64 + lane];
            float t0 = lrelu(A0 + xri) * av;
            float t1 = lrelu(A1 + xri) * av;
            float t2 = lrelu(A2 + xri) * av;
            float t3 = lrelu(A3 + xri) * av;
            t0 = dpp_add<QX1>(t0);
            t1 = dpp_add<QX1>(t1);
            t2 = dpp_add<QX1>(t2);
            t3 = dpp_add<QX1>(t3);
            float a = (lane & 1) ? t1 : t0;
            float b = (lane & 1) ? t3 : t2;
            a = dpp_add<QX2>(a);
            b = dpp_add<QX2>(b);
            float p = (lane & 2) ? b : a;
            p += __shfl_xor(p, 4);
            p += __shfl_xor(p, 8);
            p += __shfl_xor(p, 16);
            p += __shfl_xor(p, 32);
            p = (k + lane3 < nb4) ? p : -1e30f;
            float q = dpp_max<QX1>(p);
            q = dpp_max<QX2>(q);
            const float nm = fmaxf(m, q);
            const float sc = __expf(m - nm);
            const float w = __expf(p - nm);
            float sw = dpp_add<QX1>(w);
            sw = dpp_add<QX2>(sw);
            s = fmaf(s, sc, sw);
            m = nm;
            const int wi = __float_as_int(w);
            const float w0 = __int_as_float(__builtin_amdgcn_readlane(wi, 0));
            const float w1 = __int_as_float(__builtin_amdgcn_readlane(wi, 1));
            const float w2 = __int_as_float(__builtin_amdgcn_readlane(wi, 2));
            const float w3 = __int_as_float(__builtin_amdgcn_readlane(wi, 3));
            acc = fmaf(w3, A3, fmaf(w2, A2, fmaf(w1, A1, fmaf(w0, A0, acc * sc))));
        }
    }
    const float v = fmaxf(fmaf(acc, 1.0f / s, bias[lane]), 0.0f);

    float res = 0.0f;
#pragma unroll
    for (int c2 = 0; c2 < 10; c2 += 2) {
        const float2 r = wsum2(v * Wfc[lane * 10 + c2], v * Wfc[lane * 10 + c2 + 1]);
        if (lane == c2) res = r.x + bfc[c2];
        if (lane == c2 + 1) res = r.y + bfc[c2 + 1];
    }
    if (lane < 10) out[(size_t)node * 10 + lane] = res;
}

// ---------------- launch ----------------
static inline size_t align256(size_t x) { return (x + 255) & ~(size_t)255; }

extern "C" void kernel_launch(void* const* d_in, const int* in_sizes, int n_in,
                              void* d_out, int out_size, void* d_ws, size_t ws_size,
                              hipStream_t stream) {
    const int N = N_NODES, E = N_EDGES;
    const float* x    = (const float*)d_in[0];
    const int*   ei   = (const int*)d_in[1];
    const float* Wl1  = (const float*)d_in[2];
    const float* Wr1  = (const float*)d_in[3];
    const float* att1 = (const float*)d_in[4];
    const float* b1   = (const float*)d_in[5];
    const float* Wl2  = (const float*)d_in[6];
    const float* Wr2  = (const float*)d_in[7];
    const float* att2 = (const float*)d_in[8];
    const float* b2   = (const float*)d_in[9];
    const float* Wfc  = (const float*)d_in[10];
    const float* bfc  = (const float*)d_in[11];
    float* out = (float*)d_out;

    const int* src = ei;
    const int* dst = ei + E;

    char* base = (char*)d_ws;
    size_t off = 0;
    int* ptr  = (int*)(base + off); off = align256(off + (size_t)(N + 1) * 4);
    int* cnt  = (int*)(base + off); off = align256(off + (size_t)N * 4);
    int* bs   = (int*)(base + off); off = align256(off + 256 * 4);
    int* csrc = (int*)(base + off); off = align256(off + (size_t)E * 4);
    float* xl1 = (float*)(base + off); off = align256(off + (size_t)N * 128 * 4);
    float* xr1 = (float*)(base + off); off = align256(off + (size_t)N * 128 * 4);
    float* h1  = (float*)(base + off); off = align256(off + (size_t)N * 128 * 4);
    float* xl2 = xl1;
    float* xr2 = xl1 + (size_t)N * 64;

    const int nb = (N + 255) / 256;
    const int ngb = (N + 127) / 128;

    k_zero<<<nb, 256, 0, stream>>>(cnt, N);
    k_hist<<<(E + 255) / 256, 256, 0, stream>>>(dst, cnt, E);
    k_scan_local<<<nb, 256, 0, stream>>>(cnt, ptr, bs, N);
    k_scan_top<<<1, 256, 0, stream>>>(bs, nb);
    k_scan_add<<<nb, 256, 0, stream>>>(ptr, bs, cnt, N, E);
    k_scatter<<<(E + 255) / 256, 256, 0, stream>>>(src, dst, ptr, cnt, csrc, E);

    // layer 1: xl1/xr1 standard [N][128]
    k_gemm_v2<true><<<dim3(ngb, 2), 256, 0, stream>>>(x, N, Wl1, Wr1, xl1, xr1);
    k_agg1<<<(N + 3) / 4, 256, 0, stream>>>(xl1, xr1, att1, b1, ptr, csrc, h1);
    // layer 2: [N][64] x2
    k_gemm_v2<false><<<dim3(ngb, 1), 256, 0, stream>>>(h1, N, Wl2, Wr2, xl2, xr2);
    k_agg2_fc<<<(N + 3) / 4, 256, 0, stream>>>(xl2, xr2, att2, b2, ptr, csrc, Wfc, bfc, out);
}

// Round 6
// 267.336 us; speedup vs baseline: 2.1598x; 1.0938x over previous
//
#include <hip/hip_runtime.h>

#define N_NODES 50000
#define N_EDGES 800000

// DPP controls: quad_perm xor1=[1,0,3,2]=0xB1, xor2=[2,3,0,1]=0x4E,
// broadcasts [e,e,e,e], row_ror:4=0x124, row_ror:8=0x128
#define QX1 0xB1
#define QX2 0x4E
#define RR4 0x124
#define RR8 0x128
#define QB0 0x00
#define QB1 0x55
#define QB2 0xAA
#define QB3 0xFF

template <int CTRL>
__device__ __forceinline__ float dpp_add(float x) {
    int xi = __float_as_int(x);
    int yi = __builtin_amdgcn_update_dpp(xi, xi, CTRL, 0xF, 0xF, false);
    return x + __int_as_float(yi);
}
template <int CTRL>
__device__ __forceinline__ float dpp_max(float x) {
    int xi = __float_as_int(x);
    int yi = __builtin_amdgcn_update_dpp(xi, xi, CTRL, 0xF, 0xF, false);
    return fmaxf(x, __int_as_float(yi));
}
template <int CTRL>
__device__ __forceinline__ float dpp_mov(float x) {
    int xi = __float_as_int(x);
    return __int_as_float(__builtin_amdgcn_update_dpp(xi, xi, CTRL, 0xF, 0xF, false));
}

__device__ __forceinline__ float lrelu(float x) { return fmaxf(x, 0.2f * x); }

// ---------------- CSR build ----------------
__global__ void k_hist(const int* __restrict__ dst, int* __restrict__ cnt, int E) {
    int e = blockIdx.x * blockDim.x + threadIdx.x;
    if (e < E) atomicAdd(&cnt[dst[e]], 1);
}

__global__ void k_scan_local(const int* __restrict__ cnt, int* __restrict__ ptr,
                             int* __restrict__ bs, int n) {
    __shared__ int tmp[256];
    int t = threadIdx.x;
    int i = blockIdx.x * 256 + t;
    int v = (i < n) ? cnt[i] : 0;
    tmp[t] = v;
    __syncthreads();
    for (int d = 1; d < 256; d <<= 1) {
        int add = (t >= d) ? tmp[t - d] : 0;
        __syncthreads();
        tmp[t] += add;
        __syncthreads();
    }
    if (i < n) ptr[i] = tmp[t] - v;
    if (t == 255) bs[blockIdx.x] = tmp[255];
}

__global__ void k_scan_top(int* __restrict__ bs, int nb) {
    __shared__ int tmp[256];
    int t = threadIdx.x;
    int v = (t < nb) ? bs[t] : 0;
    tmp[t] = v;
    __syncthreads();
    for (int d = 1; d < 256; d <<= 1) {
        int add = (t >= d) ? tmp[t - d] : 0;
        __syncthreads();
        tmp[t] += add;
        __syncthreads();
    }
    if (t < nb) bs[t] = tmp[t] - v;
}

__global__ void k_scan_add(int* __restrict__ ptr, const int* __restrict__ bs,
                           int* __restrict__ cnt, int n, int E) {
    int i = blockIdx.x * 256 + threadIdx.x;
    if (i < n) {
        ptr[i] += bs[blockIdx.x];
        cnt[i] = 0;
    }
    if (i == 0) ptr[n] = E;
}

__global__ void k_scatter(const int* __restrict__ src, const int* __restrict__ dst,
                          const int* __restrict__ ptr, int* __restrict__ cnt,
                          int* __restrict__ csrc, int E) {
    int e = blockIdx.x * blockDim.x + threadIdx.x;
    if (e < E) {
        int i = dst[e];
        int pos = ptr[i] + atomicAdd(&cnt[i], 1);
        csrc[pos] = src[e];
    }
}

// ---------------- GEMM: 128x128 register-tiled, K=128 ----------------
template <bool WIDE>
__global__ __launch_bounds__(256)
void k_gemm_v2(const float* __restrict__ X, int nrows,
               const float* __restrict__ W0, const float* __restrict__ W1,
               float* __restrict__ Y0, float* __restrict__ Y1) {
    constexpr int BK = 32;
    __shared__ float xsT[BK][132];
    __shared__ float ws[BK][128];
    const int t = threadIdx.x;
    const int tx = t & 15, ty = t >> 4;
    const int row0 = blockIdx.x * 128;

    const float* Wa;
    const float* Wb;
    int ldw;
    float* Ya;
    float* Yb;
    if (WIDE) {
        const float* W = blockIdx.y ? W1 : W0;
        Wa = W;
        Wb = W + 64;
        ldw = 128;
        Ya = blockIdx.y ? Y1 : Y0;
        Yb = nullptr;
    } else {
        Wa = W0;
        Wb = W1;
        ldw = 64;
        Ya = Y0;
        Yb = Y1;
    }

    float acc[8][8] = {};

    for (int kc = 0; kc < 128; kc += BK) {
        __syncthreads();
        {
            const int row = t & 127;
            const int rg = min(row0 + row, nrows - 1);
            const float* xr = &X[(size_t)rg * 128 + kc];
#pragma unroll
            for (int i = 0; i < 4; ++i) {
                const int k0 = ((t >> 7) + 2 * i) * 4;
                float4 v = *(const float4*)&xr[k0];
                xsT[k0 + 0][row] = v.x;
                xsT[k0 + 1][row] = v.y;
                xsT[k0 + 2][row] = v.z;
                xsT[k0 + 3][row] = v.w;
            }
        }
#pragma unroll
        for (int i = 0; i < 4; ++i) {
            const int f4 = t + i * 256;
            const int k = f4 >> 5;
            const int c4 = (f4 & 31) * 4;
            const float* Wsrc = (c4 < 64) ? Wa : Wb;
            const int cc = (c4 < 64) ? c4 : c4 - 64;
            *(float4*)&ws[k][c4] = *(const float4*)&Wsrc[(size_t)(kc + k) * ldw + cc];
        }
        __syncthreads();
#pragma unroll 4
        for (int k = 0; k < BK; ++k) {
            const float4 a0 = *(const float4*)&xsT[k][ty * 4];
            const float4 a1 = *(const float4*)&xsT[k][ty * 4 + 64];
            const float4 b0 = *(const float4*)&ws[k][tx * 4];
            const float4 b1 = *(const float4*)&ws[k][tx * 4 + 64];
            const float ar[8] = {a0.x, a0.y, a0.z, a0.w, a1.x, a1.y, a1.z, a1.w};
            const float br[8] = {b0.x, b0.y, b0.z, b0.w, b1.x, b1.y, b1.z, b1.w};
#pragma unroll
            for (int i = 0; i < 8; ++i)
#pragma unroll
                for (int j = 0; j < 8; ++j)
                    acc[i][j] = fmaf(ar[i], br[j], acc[i][j]);
        }
    }

#pragma unroll
    for (int i = 0; i < 8; ++i) {
        const int r = row0 + ty * 4 + (i & 3) + (i >> 2) * 64;
        if (r >= nrows) continue;
        if (WIDE) {
            *(float4*)&Ya[(size_t)r * 128 + tx * 4] =
                make_float4(acc[i][0], acc[i][1], acc[i][2], acc[i][3]);
            *(float4*)&Ya[(size_t)r * 128 + 64 + tx * 4] =
                make_float4(acc[i][4], acc[i][5], acc[i][6], acc[i][7]);
        } else {
            *(float4*)&Ya[(size_t)r * 64 + tx * 4] =
                make_float4(acc[i][0], acc[i][1], acc[i][2], acc[i][3]);
            *(float4*)&Yb[(size_t)r * 64 + tx * 4] =
                make_float4(acc[i][4], acc[i][5], acc[i][6], acc[i][7]);
        }
    }
}

// ---------------- layer-1 fused GATv2 aggregation ([N][128]) ----------------
// lane l: channels 2l,2l+1 of head (l>>5). 4-edge packed quads; all reduces DPP
// except one shfl_xor(16); weight broadcast via quad_perm.
__global__ __launch_bounds__(256) void k_agg1(
    const float* __restrict__ xl, const float* __restrict__ xr,
    const float* __restrict__ att, const float* __restrict__ bias,
    const int* __restrict__ ptr, const int* __restrict__ csrc,
    float* __restrict__ out) {
    const int node = blockIdx.x * 4 + (threadIdx.x >> 6);
    const int lane = threadIdx.x & 63;
    if (node >= N_NODES) return;
    const size_t nb = (size_t)node * 128;
    const float2 xri = *(const float2*)&xr[nb + 2 * lane];
    const float2 atv = *(const float2*)&att[2 * lane];
    const int lane3 = lane & 3;

    // self loop
    const float2 xs = *(const float2*)&xl[nb + 2 * lane];
    float m, s, acc0, acc1;
    {
        float t = lrelu(xs.x + xri.x) * atv.x + lrelu(xs.y + xri.y) * atv.y;
        t = dpp_add<QX1>(t);
        t = dpp_add<QX2>(t);
        t = dpp_add<RR4>(t);
        t = dpp_add<RR8>(t);
        t += __shfl_xor(t, 16);
        m = t;
        s = 1.0f;
        acc0 = xs.x;
        acc1 = xs.y;
    }

    const int e0 = ptr[node];
    const int deg = ptr[node + 1] - e0;
    for (int base = 0; base < deg; base += 64) {
        const int nv = deg - base;
        const int idx = csrc[e0 + base + min(lane, nv - 1)];
        const int nb4 = min(nv, 64);
        for (int k = 0; k < nb4; k += 4) {
            const int j0 = __builtin_amdgcn_readlane(idx, k);
            const int j1 = __builtin_amdgcn_readlane(idx, min(k + 1, nb4 - 1));
            const int j2 = __builtin_amdgcn_readlane(idx, min(k + 2, nb4 - 1));
            const int j3 = __builtin_amdgcn_readlane(idx, min(k + 3, nb4 - 1));
            const float2 A0 = *(const float2*)&xl[(size_t)j0 * 128 + 2 * lane];
            const float2 A1 = *(const float2*)&xl[(size_t)j1 * 128 + 2 * lane];
            const float2 A2 = *(const float2*)&xl[(size_t)j2 * 128 + 2 * lane];
            const float2 A3 = *(const float2*)&xl[(size_t)j3 * 128 + 2 * lane];
            float t0 = lrelu(A0.x + xri.x) * atv.x + lrelu(A0.y + xri.y) * atv.y;
            float t1 = lrelu(A1.x + xri.x) * atv.x + lrelu(A1.y + xri.y) * atv.y;
            float t2 = lrelu(A2.x + xri.x) * atv.x + lrelu(A2.y + xri.y) * atv.y;
            float t3 = lrelu(A3.x + xri.x) * atv.x + lrelu(A3.y + xri.y) * atv.y;
            // packed tree reduce: edge -> lane bits 0,1; channel sum across quads
            t0 = dpp_add<QX1>(t0);
            t1 = dpp_add<QX1>(t1);
            t2 = dpp_add<QX1>(t2);
            t3 = dpp_add<QX1>(t3);
            float a = (lane & 1) ? t1 : t0;
            float b = (lane & 1) ? t3 : t2;
            a = dpp_add<QX2>(a);
            b = dpp_add<QX2>(b);
            float p = (lane & 2) ? b : a;
            p = dpp_add<RR4>(p);
            p = dpp_add<RR8>(p);
            p += __shfl_xor(p, 16);
            p = (k + lane3 < nb4) ? p : -1e30f;
            // online-softmax merge (per 32-lane head-half, packed)
            float q = dpp_max<QX1>(p);
            q = dpp_max<QX2>(q);
            const float nm = fmaxf(m, q);
            const float sc = __expf(m - nm);
            const float w = __expf(p - nm);
            float sw = dpp_add<QX1>(w);
            sw = dpp_add<QX2>(sw);
            s = fmaf(s, sc, sw);
            m = nm;
            const float w0 = dpp_mov<QB0>(w);
            const float w1 = dpp_mov<QB1>(w);
            const float w2 = dpp_mov<QB2>(w);
            const float w3 = dpp_mov<QB3>(w);
            acc0 = fmaf(w3, A3.x, fmaf(w2, A2.x, fmaf(w1, A1.x, fmaf(w0, A0.x, acc0 * sc))));
            acc1 = fmaf(w3, A3.y, fmaf(w2, A2.y, fmaf(w1, A1.y, fmaf(w0, A0.y, acc1 * sc))));
        }
    }
    const float inv = 1.0f / s;
    float2 o;
    o.x = fmaxf(fmaf(acc0, inv, bias[2 * lane]), 0.0f);
    o.y = fmaxf(fmaf(acc1, inv, bias[2 * lane + 1]), 0.0f);
    *(float2*)&out[nb + 2 * lane] = o;
}

// ---------------- layer-2 aggregation + fused FC head ----------------
// 2 nodes per wave: lanes 0-31 node A, 32-63 node B; lane holds channels 2*(l&31), +1.
// Reduces use quad DPP + ror4/ror8 + xor16 only — never cross bit5.
__global__ __launch_bounds__(256) void k_agg2_fc(
    const float* __restrict__ xl, const float* __restrict__ xr,
    const float* __restrict__ att, const float* __restrict__ bias,
    const int* __restrict__ ptr, const int* __restrict__ csrc,
    const float* __restrict__ Wfc, const float* __restrict__ bfc,
    float* __restrict__ out) {
    const int wid = blockIdx.x * 4 + (threadIdx.x >> 6);
    const int lane = threadIdx.x & 63;
    const int hl = lane & 31;
    const int node = wid * 2 + (lane >> 5);  // N even, grid exact
    const int lane3 = lane & 3;
    const size_t nbo = (size_t)node * 64;
    const float2 xri = *(const float2*)&xr[nbo + 2 * hl];
    const float2 atv = *(const float2*)&att[2 * hl];

    // self loop
    const float2 xs = *(const float2*)&xl[nbo + 2 * hl];
    float m, s, acc0, acc1;
    {
        float t = lrelu(xs.x + xri.x) * atv.x + lrelu(xs.y + xri.y) * atv.y;
        t = dpp_add<QX1>(t);
        t = dpp_add<QX2>(t);
        t = dpp_add<RR4>(t);
        t = dpp_add<RR8>(t);
        t += __shfl_xor(t, 16);
        m = t;
        s = 1.0f;
        acc0 = xs.x;
        acc1 = xs.y;
    }

    const int e0 = ptr[node];
    const int deg = ptr[node + 1] - e0;
    const int degw = max(deg, __shfl_xor(deg, 32));  // wave loop bound
    for (int base = 0; base < degw; base += 32) {
        const int nv = deg - base;                 // may be <= 0 for my half
        const int nb4 = min(nv, 32);
        const int off = max(0, min(hl, nv - 1));
        const int ee = min(e0 + base + off, N_EDGES - 1);
        const int idx = csrc[ee];
        const int kmax = min(32, degw - base);
        for (int k = 0; k < kmax; k += 4) {
            const int b0 = ((lane & 32) + k) << 2;  // bpermute: my half's edge k..k+3
            const int j0 = __builtin_amdgcn_ds_bpermute(b0, idx);
            const int j1 = __builtin_amdgcn_ds_bpermute(b0 + 4, idx);
            const int j2 = __builtin_amdgcn_ds_bpermute(b0 + 8, idx);
            const int j3 = __builtin_amdgcn_ds_bpermute(b0 + 12, idx);
            const float2 A0 = *(const float2*)&xl[(size_t)j0 * 64 + 2 * hl];
            const float2 A1 = *(const float2*)&xl[(size_t)j1 * 64 + 2 * hl];
            const float2 A2 = *(const float2*)&xl[(size_t)j2 * 64 + 2 * hl];
            const float2 A3 = *(const float2*)&xl[(size_t)j3 * 64 + 2 * hl];
            float t0 = lrelu(A0.x + xri.x) * atv.x + lrelu(A0.y + xri.y) * atv.y;
            float t1 = lrelu(A1.x + xri.x) * atv.x + lrelu(A1.y + xri.y) * atv.y;
            float t2 = lrelu(A2.x + xri.x) * atv.x + lrelu(A2.y + xri.y) * atv.y;
            float t3 = lrelu(A3.x + xri.x) * atv.x + lrelu(A3.y + xri.y) * atv.y;
            t0 = dpp_add<QX1>(t0);
            t1 = dpp_add<QX1>(t1);
            t2 = dpp_add<QX1>(t2);
            t3 = dpp_add<QX1>(t3);
            float a = (lane & 1) ? t1 : t0;
            float b = (lane & 1) ? t3 : t2;
            a = dpp_add<QX2>(a);
            b = dpp_add<QX2>(b);
            float p = (lane & 2) ? b : a;
            p = dpp_add<RR4>(p);
            p = dpp_add<RR8>(p);
            p += __shfl_xor(p, 16);
            p = (k + lane3 < nb4) ? p : -1e30f;
            float q = dpp_max<QX1>(p);
            q = dpp_max<QX2>(q);
            const float nm = fmaxf(m, q);
            const float sc = __expf(m - nm);
            const float w = __expf(p - nm);
            float sw = dpp_add<QX1>(w);
            sw = dpp_add<QX2>(sw);
            s = fmaf(s, sc, sw);
            m = nm;
            const float w0 = dpp_mov<QB0>(w);
            const float w1 = dpp_mov<QB1>(w);
            const float w2 = dpp_mov<QB2>(w);
            const float w3 = dpp_mov<QB3>(w);
            acc0 = fmaf(w3, A3.x, fmaf(w2, A2.x, fmaf(w1, A1.x, fmaf(w0, A0.x, acc0 * sc))));
            acc1 = fmaf(w3, A3.y, fmaf(w2, A2.y, fmaf(w1, A1.y, fmaf(w0, A0.y, acc1 * sc))));
        }
    }
    const float inv = 1.0f / s;
    const float v0 = fmaxf(fmaf(acc0, inv, bias[2 * hl]), 0.0f);
    const float v1 = fmaxf(fmaf(acc1, inv, bias[2 * hl + 1]), 0.0f);

    // FC head (FIXED): per group g each lane contributes its 2 channels to ALL 4
    // classes of the group, then the quad-pack tree (class -> lane bits 0,1) +
    // lane3-preserving rotations give the full 32-lane channel sum per class.
    float res = 0.0f;
#pragma unroll
    for (int g = 0; g < 3; ++g) {
        const int cb = 4 * g;
        const int c0 = cb, c1 = cb + 1;
        const int c2 = min(cb + 2, 9), c3 = min(cb + 3, 9);
        const float* w0r = &Wfc[(2 * hl) * 10];
        const float* w1r = &Wfc[(2 * hl + 1) * 10];
        float u0 = v0 * w0r[c0] + v1 * w1r[c0];
        float u1 = v0 * w0r[c1] + v1 * w1r[c1];
        float u2 = v0 * w0r[c2] + v1 * w1r[c2];
        float u3 = v0 * w0r[c3] + v1 * w1r[c3];
        u0 = dpp_add<QX1>(u0);
        u1 = dpp_add<QX1>(u1);
        u2 = dpp_add<QX1>(u2);
        u3 = dpp_add<QX1>(u3);
        float a = (lane & 1) ? u1 : u0;
        float b = (lane & 1) ? u3 : u2;
        a = dpp_add<QX2>(a);
        b = dpp_add<QX2>(b);
        float t = (lane & 2) ? b : a;
        t = dpp_add<RR4>(t);
        t = dpp_add<RR8>(t);
        t += __shfl_xor(t, 16);
        if ((hl >> 2) == g) res = t;  // lane hl holds class hl (= 4g + lane3)
    }
    if (hl < 10) out[(size_t)node * 10 + hl] = res + bfc[hl];
}

// ---------------- launch ----------------
static inline size_t align256(size_t x) { return (x + 255) & ~(size_t)255; }

extern "C" void kernel_launch(void* const* d_in, const int* in_sizes, int n_in,
                              void* d_out, int out_size, void* d_ws, size_t ws_size,
                              hipStream_t stream) {
    const int N = N_NODES, E = N_EDGES;
    const float* x    = (const float*)d_in[0];
    const int*   ei   = (const int*)d_in[1];
    const float* Wl1  = (const float*)d_in[2];
    const float* Wr1  = (const float*)d_in[3];
    const float* att1 = (const float*)d_in[4];
    const float* b1   = (const float*)d_in[5];
    const float* Wl2  = (const float*)d_in[6];
    const float* Wr2  = (const float*)d_in[7];
    const float* att2 = (const float*)d_in[8];
    const float* b2   = (const float*)d_in[9];
    const float* Wfc  = (const float*)d_in[10];
    const float* bfc  = (const float*)d_in[11];
    float* out = (float*)d_out;

    const int* src = ei;
    const int* dst = ei + E;

    char* base = (char*)d_ws;
    size_t off = 0;
    int* ptr  = (int*)(base + off); off = align256(off + (size_t)(N + 1) * 4);
    int* cnt  = (int*)(base + off); off = align256(off + (size_t)N * 4);
    int* bs   = (int*)(base + off); off = align256(off + 256 * 4);
    int* csrc = (int*)(base + off); off = align256(off + (size_t)E * 4);
    float* xl1 = (float*)(base + off); off = align256(off + (size_t)N * 128 * 4);
    float* xr1 = (float*)(base + off); off = align256(off + (size_t)N * 128 * 4);
    float* h1  = (float*)(base + off); off = align256(off + (size_t)N * 128 * 4);
    float* xl2 = xl1;
    float* xr2 = xl1 + (size_t)N * 64;

    const int nb = (N + 255) / 256;
    const int ngb = (N + 127) / 128;

    hipMemsetAsync(cnt, 0, (size_t)N * 4, stream);
    k_hist<<<(E + 255) / 256, 256, 0, stream>>>(dst, cnt, E);
    k_scan_local<<<nb, 256, 0, stream>>>(cnt, ptr, bs, N);
    k_scan_top<<<1, 256, 0, stream>>>(bs, nb);
    k_scan_add<<<nb, 256, 0, stream>>>(ptr, bs, cnt, N, E);
    k_scatter<<<(E + 255) / 256, 256, 0, stream>>>(src, dst, ptr, cnt, csrc, E);

    // layer 1: xl1/xr1 standard [N][128]
    k_gemm_v2<true><<<dim3(ngb, 2), 256, 0, stream>>>(x, N, Wl1, Wr1, xl1, xr1);
    k_agg1<<<(N + 3) / 4, 256, 0, stream>>>(xl1, xr1, att1, b1, ptr, csrc, h1);
    // layer 2: [N][64] x2
    k_gemm_v2<false><<<dim3(ngb, 1), 256, 0, stream>>>(h1, N, Wl2, Wr2, xl2, xr2);
    // 2 nodes per wave -> N/2 waves, 4 waves per block
    k_agg2_fc<<<(N / 2 + 3) / 4, 256, 0, stream>>>(xl2, xr2, att2, b2, ptr, csrc, Wfc, bfc, out);
}

// Round 7
// 236.368 us; speedup vs baseline: 2.4428x; 1.1310x over previous
//
#include <hip/hip_runtime.h>

#define N_NODES 50000
#define N_EDGES 800000

typedef float f2 __attribute__((ext_vector_type(2)));

// DPP controls: quad_perm xor1=[1,0,3,2]=0xB1, xor2=[2,3,0,1]=0x4E,
// quad broadcasts, row_ror:4=0x124, row_ror:8=0x128 (rows = 16 lanes on CDNA)
#define QX1 0xB1
#define QX2 0x4E
#define RR4 0x124
#define RR8 0x128
#define QB0 0x00
#define QB1 0x55
#define QB2 0xAA
#define QB3 0xFF

template <int CTRL>
__device__ __forceinline__ float dpp_add(float x) {
    int xi = __float_as_int(x);
    int yi = __builtin_amdgcn_update_dpp(xi, xi, CTRL, 0xF, 0xF, false);
    return x + __int_as_float(yi);
}
template <int CTRL>
__device__ __forceinline__ float dpp_max(float x) {
    int xi = __float_as_int(x);
    int yi = __builtin_amdgcn_update_dpp(xi, xi, CTRL, 0xF, 0xF, false);
    return fmaxf(x, __int_as_float(yi));
}
template <int CTRL>
__device__ __forceinline__ float dpp_mov(float x) {
    int xi = __float_as_int(x);
    return __int_as_float(__builtin_amdgcn_update_dpp(xi, xi, CTRL, 0xF, 0xF, false));
}

// per-lane 2-channel logit contribution (packed f32 ops); atv pre-scaled by log2e
__device__ __forceinline__ float logit2(f2 A, f2 xri, f2 atv) {
    f2 u = A + xri;
    f2 l = __builtin_elementwise_max(u, 0.2f * u);
    f2 d = l * atv;
    return d.x + d.y;
}

// pack 4 per-edge partials to lane bits 0,1 and sum over the 32-lane half.
// result: lane holds full sum for edge (lane&3), replicated across its half.
__device__ __forceinline__ float quadtree(float t0, float t1, float t2, float t3, int lane) {
    t0 = dpp_add<QX1>(t0);
    t1 = dpp_add<QX1>(t1);
    t2 = dpp_add<QX1>(t2);
    t3 = dpp_add<QX1>(t3);
    float a = (lane & 1) ? t1 : t0;
    float b = (lane & 1) ? t3 : t2;
    a = dpp_add<QX2>(a);
    b = dpp_add<QX2>(b);
    float p = (lane & 2) ? b : a;
    p = dpp_add<RR4>(p);
    p = dpp_add<RR8>(p);
    p += __shfl_xor(p, 16);
    return p;
}

// ---------------- CSR build (single atomic pass + rank) ----------------
__global__ void k_hist(const int* __restrict__ dst, int* __restrict__ cnt,
                       unsigned short* __restrict__ rank, int E) {
    int e = blockIdx.x * blockDim.x + threadIdx.x;
    if (e < E) rank[e] = (unsigned short)atomicAdd(&cnt[dst[e]], 1);
}

__global__ void k_scan_local(const int* __restrict__ cnt, int* __restrict__ ptr,
                             int* __restrict__ bs, int n) {
    __shared__ int tmp[256];
    int t = threadIdx.x;
    int i = blockIdx.x * 256 + t;
    int v = (i < n) ? cnt[i] : 0;
    tmp[t] = v;
    __syncthreads();
    for (int d = 1; d < 256; d <<= 1) {
        int add = (t >= d) ? tmp[t - d] : 0;
        __syncthreads();
        tmp[t] += add;
        __syncthreads();
    }
    if (i < n) ptr[i] = tmp[t] - v;
    if (t == 255) bs[blockIdx.x] = tmp[255];
}

// adds prefix of block sums (recomputed locally; kills the separate top-scan kernel)
__global__ void k_scan_add2(int* __restrict__ ptr, const int* __restrict__ bs,
                            int n, int nbk, int E) {
    __shared__ int sh[256];
    int t = threadIdx.x;
    sh[t] = (t < nbk && t < blockIdx.x) ? bs[t] : 0;
    __syncthreads();
    for (int d = 128; d; d >>= 1) {
        if (t < d) sh[t] += sh[t + d];
        __syncthreads();
    }
    const int off = sh[0];
    int i = blockIdx.x * 256 + t;
    if (i < n) ptr[i] += off;
    if (i == 0) ptr[n] = E;
}

__global__ void k_scatter(const int* __restrict__ src, const int* __restrict__ dst,
                          const int* __restrict__ ptr, const unsigned short* __restrict__ rank,
                          int* __restrict__ csrc, int E) {
    int e = blockIdx.x * blockDim.x + threadIdx.x;
    if (e < E) csrc[ptr[dst[e]] + rank[e]] = src[e];
}

// ---------------- GEMM: 128x128 register-tiled, K=128 ----------------
template <bool WIDE>
__global__ __launch_bounds__(256)
void k_gemm_v2(const float* __restrict__ X, int nrows,
               const float* __restrict__ W0, const float* __restrict__ W1,
               float* __restrict__ Y0, float* __restrict__ Y1) {
    constexpr int BK = 32;
    __shared__ float xsT[BK][132];
    __shared__ float ws[BK][128];
    const int t = threadIdx.x;
    const int tx = t & 15, ty = t >> 4;
    const int row0 = blockIdx.x * 128;

    const float* Wa;
    const float* Wb;
    int ldw;
    float* Ya;
    float* Yb;
    if (WIDE) {
        const float* W = blockIdx.y ? W1 : W0;
        Wa = W;
        Wb = W + 64;
        ldw = 128;
        Ya = blockIdx.y ? Y1 : Y0;
        Yb = nullptr;
    } else {
        Wa = W0;
        Wb = W1;
        ldw = 64;
        Ya = Y0;
        Yb = Y1;
    }

    float acc[8][8] = {};

    for (int kc = 0; kc < 128; kc += BK) {
        __syncthreads();
        {
            const int row = t & 127;
            const int rg = min(row0 + row, nrows - 1);
            const float* xr = &X[(size_t)rg * 128 + kc];
#pragma unroll
            for (int i = 0; i < 4; ++i) {
                const int k0 = ((t >> 7) + 2 * i) * 4;
                float4 v = *(const float4*)&xr[k0];
                xsT[k0 + 0][row] = v.x;
                xsT[k0 + 1][row] = v.y;
                xsT[k0 + 2][row] = v.z;
                xsT[k0 + 3][row] = v.w;
            }
        }
#pragma unroll
        for (int i = 0; i < 4; ++i) {
            const int f4 = t + i * 256;
            const int k = f4 >> 5;
            const int c4 = (f4 & 31) * 4;
            const float* Wsrc = (c4 < 64) ? Wa : Wb;
            const int cc = (c4 < 64) ? c4 : c4 - 64;
            *(float4*)&ws[k][c4] = *(const float4*)&Wsrc[(size_t)(kc + k) * ldw + cc];
        }
        __syncthreads();
#pragma unroll 4
        for (int k = 0; k < BK; ++k) {
            const float4 a0 = *(const float4*)&xsT[k][ty * 4];
            const float4 a1 = *(const float4*)&xsT[k][ty * 4 + 64];
            const float4 b0 = *(const float4*)&ws[k][tx * 4];
            const float4 b1 = *(const float4*)&ws[k][tx * 4 + 64];
            const float ar[8] = {a0.x, a0.y, a0.z, a0.w, a1.x, a1.y, a1.z, a1.w};
            const float br[8] = {b0.x, b0.y, b0.z, b0.w, b1.x, b1.y, b1.z, b1.w};
#pragma unroll
            for (int i = 0; i < 8; ++i)
#pragma unroll
                for (int j = 0; j < 8; ++j)
                    acc[i][j] = fmaf(ar[i], br[j], acc[i][j]);
        }
    }

#pragma unroll
    for (int i = 0; i < 8; ++i) {
        const int r = row0 + ty * 4 + (i & 3) + (i >> 2) * 64;
        if (r >= nrows) continue;
        if (WIDE) {
            *(float4*)&Ya[(size_t)r * 128 + tx * 4] =
                make_float4(acc[i][0], acc[i][1], acc[i][2], acc[i][3]);
            *(float4*)&Ya[(size_t)r * 128 + 64 + tx * 4] =
                make_float4(acc[i][4], acc[i][5], acc[i][6], acc[i][7]);
        } else {
            *(float4*)&Ya[(size_t)r * 64 + tx * 4] =
                make_float4(acc[i][0], acc[i][1], acc[i][2], acc[i][3]);
            *(float4*)&Yb[(size_t)r * 64 + tx * 4] =
                make_float4(acc[i][4], acc[i][5], acc[i][6], acc[i][7]);
        }
    }
}

// ---------------- layer-1 fused GATv2 aggregation ([N][128]) ----------------
// lane l: channels 2l,2l+1 of head (l>>5). 8-edge blocks (two quad trees, ONE merge);
// packed-f32 channel math; log2-domain softmax (att pre-scaled by log2e).
__global__ __launch_bounds__(256) void k_agg1(
    const float* __restrict__ xl, const float* __restrict__ xr,
    const float* __restrict__ att, const float* __restrict__ bias,
    const int* __restrict__ ptr, const int* __restrict__ csrc,
    float* __restrict__ out) {
    const int node = blockIdx.x * 4 + (threadIdx.x >> 6);
    const int lane = threadIdx.x & 63;
    if (node >= N_NODES) return;
    const size_t nb = (size_t)node * 128;
    const f2 xri = *(const f2*)&xr[nb + 2 * lane];
    f2 atv = *(const f2*)&att[2 * lane];
    atv *= 1.44269504088896340736f;  // log2(e): softmax in exp2 domain
    const int lane3 = lane & 3;

    const f2 xs = *(const f2*)&xl[nb + 2 * lane];
    f2 acc;
    float m, s;
    {
        float t = logit2(xs, xri, atv);
        t = dpp_add<QX1>(t);
        t = dpp_add<QX2>(t);
        t = dpp_add<RR4>(t);
        t = dpp_add<RR8>(t);
        t += __shfl_xor(t, 16);
        m = t;
        s = 1.0f;
        acc = xs;
    }

    const int e0 = ptr[node];
    const int deg = ptr[node + 1] - e0;
    for (int base = 0; base < deg; base += 64) {
        const int nv = deg - base;
        const int idx = csrc[e0 + base + min(lane, nv - 1)];
        const int nb4 = min(nv, 64);
        for (int k = 0; k < nb4; k += 8) {
            const int j0 = __builtin_amdgcn_readlane(idx, k);
            const int j1 = __builtin_amdgcn_readlane(idx, min(k + 1, nb4 - 1));
            const int j2 = __builtin_amdgcn_readlane(idx, min(k + 2, nb4 - 1));
            const int j3 = __builtin_amdgcn_readlane(idx, min(k + 3, nb4 - 1));
            const int j4 = __builtin_amdgcn_readlane(idx, min(k + 4, nb4 - 1));
            const int j5 = __builtin_amdgcn_readlane(idx, min(k + 5, nb4 - 1));
            const int j6 = __builtin_amdgcn_readlane(idx, min(k + 6, nb4 - 1));
            const int j7 = __builtin_amdgcn_readlane(idx, min(k + 7, nb4 - 1));
            // uniform row base (SGPR) + per-lane 8B offset -> saddr loads
            const f2 A0 = *(const f2*)(xl + ((size_t)j0 << 7) + 2 * lane);
            const f2 A1 = *(const f2*)(xl + ((size_t)j1 << 7) + 2 * lane);
            const f2 A2 = *(const f2*)(xl + ((size_t)j2 << 7) + 2 * lane);
            const f2 A3 = *(const f2*)(xl + ((size_t)j3 << 7) + 2 * lane);
            const f2 A4 = *(const f2*)(xl + ((size_t)j4 << 7) + 2 * lane);
            const f2 A5 = *(const f2*)(xl + ((size_t)j5 << 7) + 2 * lane);
            const f2 A6 = *(const f2*)(xl + ((size_t)j6 << 7) + 2 * lane);
            const f2 A7 = *(const f2*)(xl + ((size_t)j7 << 7) + 2 * lane);
            const float t0 = logit2(A0, xri, atv);
            const float t1 = logit2(A1, xri, atv);
            const float t2 = logit2(A2, xri, atv);
            const float t3 = logit2(A3, xri, atv);
            const float t4 = logit2(A4, xri, atv);
            const float t5 = logit2(A5, xri, atv);
            const float t6 = logit2(A6, xri, atv);
            const float t7 = logit2(A7, xri, atv);
            float pA = quadtree(t0, t1, t2, t3, lane);
            float pB = quadtree(t4, t5, t6, t7, lane);
            pA = (k + lane3 < nb4) ? pA : -1e30f;
            pB = (k + 4 + lane3 < nb4) ? pB : -1e30f;
            // single merge for 8 edges
            float q = fmaxf(pA, pB);
            q = dpp_max<QX1>(q);
            q = dpp_max<QX2>(q);
            const float nm = fmaxf(m, q);
            const float sc = __builtin_amdgcn_exp2f(m - nm);
            const float wA = __builtin_amdgcn_exp2f(pA - nm);
            const float wB = __builtin_amdgcn_exp2f(pB - nm);
            float sw = wA + wB;
            sw = dpp_add<QX1>(sw);
            sw = dpp_add<QX2>(sw);
            s = fmaf(s, sc, sw);
            m = nm;
            const float w0 = dpp_mov<QB0>(wA), w1 = dpp_mov<QB1>(wA);
            const float w2 = dpp_mov<QB2>(wA), w3 = dpp_mov<QB3>(wA);
            const float w4 = dpp_mov<QB0>(wB), w5 = dpp_mov<QB1>(wB);
            const float w6 = dpp_mov<QB2>(wB), w7 = dpp_mov<QB3>(wB);
            acc = acc * sc;
            acc += A0 * w0;
            acc += A1 * w1;
            acc += A2 * w2;
            acc += A3 * w3;
            acc += A4 * w4;
            acc += A5 * w5;
            acc += A6 * w6;
            acc += A7 * w7;
        }
    }
    const float inv = 1.0f / s;
    const f2 bv = *(const f2*)&bias[2 * lane];
    f2 o = acc * inv + bv;
    o = __builtin_elementwise_max(o, (f2)(0.0f));
    *(f2*)&out[nb + 2 * lane] = o;
}

// ---------------- layer-2 aggregation + fused FC head ----------------
// 2 nodes per wave (lanes 0-31 / 32-63); lane holds channels 2*(l&31), +1.
__global__ __launch_bounds__(256) void k_agg2_fc(
    const float* __restrict__ xl, const float* __restrict__ xr,
    const float* __restrict__ att, const float* __restrict__ bias,
    const int* __restrict__ ptr, const int* __restrict__ csrc,
    const float* __restrict__ Wfc, const float* __restrict__ bfc,
    float* __restrict__ out) {
    const int wid = blockIdx.x * 4 + (threadIdx.x >> 6);
    const int lane = threadIdx.x & 63;
    const int hl = lane & 31;
    const int node = wid * 2 + (lane >> 5);  // N even, grid exact
    const int lane3 = lane & 3;
    const size_t nbo = (size_t)node * 64;
    const f2 xri = *(const f2*)&xr[nbo + 2 * hl];
    f2 atv = *(const f2*)&att[2 * hl];
    atv *= 1.44269504088896340736f;

    const f2 xs = *(const f2*)&xl[nbo + 2 * hl];
    f2 acc;
    float m, s;
    {
        float t = logit2(xs, xri, atv);
        t = dpp_add<QX1>(t);
        t = dpp_add<QX2>(t);
        t = dpp_add<RR4>(t);
        t = dpp_add<RR8>(t);
        t += __shfl_xor(t, 16);
        m = t;
        s = 1.0f;
        acc = xs;
    }

    const int e0 = ptr[node];
    const int deg = ptr[node + 1] - e0;
    const int degw = max(deg, __shfl_xor(deg, 32));
    for (int base = 0; base < degw; base += 32) {
        const int nv = deg - base;  // may be <= 0 for my half
        const int nb4 = min(nv, 32);
        const int off = max(0, min(hl, nv - 1));
        const int ee = min(e0 + base + off, N_EDGES - 1);
        const int idx = csrc[ee];
        const int kmax = min(32, degw - base);
        for (int k = 0; k < kmax; k += 8) {
            const int b0 = ((lane & 32) + k) << 2;
            const int j0 = __builtin_amdgcn_ds_bpermute(b0, idx);
            const int j1 = __builtin_amdgcn_ds_bpermute(b0 + 4, idx);
            const int j2 = __builtin_amdgcn_ds_bpermute(b0 + 8, idx);
            const int j3 = __builtin_amdgcn_ds_bpermute(b0 + 12, idx);
            const int j4 = __builtin_amdgcn_ds_bpermute(b0 + 16, idx);
            const int j5 = __builtin_amdgcn_ds_bpermute(b0 + 20, idx);
            const int j6 = __builtin_amdgcn_ds_bpermute(b0 + 24, idx);
            const int j7 = __builtin_amdgcn_ds_bpermute(b0 + 28, idx);
            const f2 A0 = *(const f2*)(xl + (((unsigned)j0) << 6) + 2 * hl);
            const f2 A1 = *(const f2*)(xl + (((unsigned)j1) << 6) + 2 * hl);
            const f2 A2 = *(const f2*)(xl + (((unsigned)j2) << 6) + 2 * hl);
            const f2 A3 = *(const f2*)(xl + (((unsigned)j3) << 6) + 2 * hl);
            const f2 A4 = *(const f2*)(xl + (((unsigned)j4) << 6) + 2 * hl);
            const f2 A5 = *(const f2*)(xl + (((unsigned)j5) << 6) + 2 * hl);
            const f2 A6 = *(const f2*)(xl + (((unsigned)j6) << 6) + 2 * hl);
            const f2 A7 = *(const f2*)(xl + (((unsigned)j7) << 6) + 2 * hl);
            const float t0 = logit2(A0, xri, atv);
            const float t1 = logit2(A1, xri, atv);
            const float t2 = logit2(A2, xri, atv);
            const float t3 = logit2(A3, xri, atv);
            const float t4 = logit2(A4, xri, atv);
            const float t5 = logit2(A5, xri, atv);
            const float t6 = logit2(A6, xri, atv);
            const float t7 = logit2(A7, xri, atv);
            float pA = quadtree(t0, t1, t2, t3, lane);
            float pB = quadtree(t4, t5, t6, t7, lane);
            pA = (k + lane3 < nb4) ? pA : -1e30f;
            pB = (k + 4 + lane3 < nb4) ? pB : -1e30f;
            float q = fmaxf(pA, pB);
            q = dpp_max<QX1>(q);
            q = dpp_max<QX2>(q);
            const float nm = fmaxf(m, q);
            const float sc = __builtin_amdgcn_exp2f(m - nm);
            const float wA = __builtin_amdgcn_exp2f(pA - nm);
            const float wB = __builtin_amdgcn_exp2f(pB - nm);
            float sw = wA + wB;
            sw = dpp_add<QX1>(sw);
            sw = dpp_add<QX2>(sw);
            s = fmaf(s, sc, sw);
            m = nm;
            const float w0 = dpp_mov<QB0>(wA), w1 = dpp_mov<QB1>(wA);
            const float w2 = dpp_mov<QB2>(wA), w3 = dpp_mov<QB3>(wA);
            const float w4 = dpp_mov<QB0>(wB), w5 = dpp_mov<QB1>(wB);
            const float w6 = dpp_mov<QB2>(wB), w7 = dpp_mov<QB3>(wB);
            acc = acc * sc;
            acc += A0 * w0;
            acc += A1 * w1;
            acc += A2 * w2;
            acc += A3 * w3;
            acc += A4 * w4;
            acc += A5 * w5;
            acc += A6 * w6;
            acc += A7 * w7;
        }
    }
    const float inv = 1.0f / s;
    const float v0 = fmaxf(fmaf(acc.x, inv, bias[2 * hl]), 0.0f);
    const float v1 = fmaxf(fmaf(acc.y, inv, bias[2 * hl + 1]), 0.0f);

    // FC head: per group g, each lane contributes its 2 channels to all 4 classes,
    // quad-pack tree -> class at lane bits 0,1, then lane3-preserving 32-lane sum.
    float res = 0.0f;
#pragma unroll
    for (int g = 0; g < 3; ++g) {
        const int cb = 4 * g;
        const int c0 = cb, c1 = cb + 1;
        const int c2 = min(cb + 2, 9), c3 = min(cb + 3, 9);
        const float* w0r = &Wfc[(2 * hl) * 10];
        const float* w1r = &Wfc[(2 * hl + 1) * 10];
        float u0 = v0 * w0r[c0] + v1 * w1r[c0];
        float u1 = v0 * w0r[c1] + v1 * w1r[c1];
        float u2 = v0 * w0r[c2] + v1 * w1r[c2];
        float u3 = v0 * w0r[c3] + v1 * w1r[c3];
        const float t = quadtree(u0, u1, u2, u3, lane);
        if ((hl >> 2) == g) res = t;  // lane hl holds class hl (= 4g + lane3)
    }
    if (hl < 10) out[(size_t)node * 10 + hl] = res + bfc[hl];
}

// ---------------- launch ----------------
static inline size_t align256(size_t x) { return (x + 255) & ~(size_t)255; }

extern "C" void kernel_launch(void* const* d_in, const int* in_sizes, int n_in,
                              void* d_out, int out_size, void* d_ws, size_t ws_size,
                              hipStream_t stream) {
    const int N = N_NODES, E = N_EDGES;
    const float* x    = (const float*)d_in[0];
    const int*   ei   = (const int*)d_in[1];
    const float* Wl1  = (const float*)d_in[2];
    const float* Wr1  = (const float*)d_in[3];
    const float* att1 = (const float*)d_in[4];
    const float* b1   = (const float*)d_in[5];
    const float* Wl2  = (const float*)d_in[6];
    const float* Wr2  = (const float*)d_in[7];
    const float* att2 = (const float*)d_in[8];
    const float* b2   = (const float*)d_in[9];
    const float* Wfc  = (const float*)d_in[10];
    const float* bfc  = (const float*)d_in[11];
    float* out = (float*)d_out;

    const int* src = ei;
    const int* dst = ei + E;

    char* base = (char*)d_ws;
    size_t off = 0;
    int* ptr  = (int*)(base + off); off = align256(off + (size_t)(N + 1) * 4);
    int* cnt  = (int*)(base + off); off = align256(off + (size_t)N * 4);
    int* bs   = (int*)(base + off); off = align256(off + 256 * 4);
    unsigned short* rank = (unsigned short*)(base + off); off = align256(off + (size_t)E * 2);
    int* csrc = (int*)(base + off); off = align256(off + (size_t)E * 4);
    float* xl1 = (float*)(base + off); off = align256(off + (size_t)N * 128 * 4);
    float* xr1 = (float*)(base + off); off = align256(off + (size_t)N * 128 * 4);
    float* h1  = (float*)(base + off); off = align256(off + (size_t)N * 128 * 4);
    float* xl2 = xl1;
    float* xr2 = xl1 + (size_t)N * 64;

    const int nb = (N + 255) / 256;   // 196
    const int ngb = (N + 127) / 128;

    hipMemsetAsync(cnt, 0, (size_t)N * 4, stream);
    k_hist<<<(E + 255) / 256, 256, 0, stream>>>(dst, cnt, rank, E);
    k_scan_local<<<nb, 256, 0, stream>>>(cnt, ptr, bs, N);
    k_scan_add2<<<nb, 256, 0, stream>>>(ptr, bs, N, nb, E);
    k_scatter<<<(E + 255) / 256, 256, 0, stream>>>(src, dst, ptr, rank, csrc, E);

    // layer 1: xl1/xr1 standard [N][128]
    k_gemm_v2<true><<<dim3(ngb, 2), 256, 0, stream>>>(x, N, Wl1, Wr1, xl1, xr1);
    k_agg1<<<(N + 3) / 4, 256, 0, stream>>>(xl1, xr1, att1, b1, ptr, csrc, h1);
    // layer 2: [N][64] x2
    k_gemm_v2<false><<<dim3(ngb, 1), 256, 0, stream>>>(h1, N, Wl2, Wr2, xl2, xr2);
    k_agg2_fc<<<(N / 2 + 3) / 4, 256, 0, stream>>>(xl2, xr2, att2, b2, ptr, csrc, Wfc, bfc, out);
}